// Round 14
// baseline (141.374 us; speedup 1.0000x reference)
//
#include <hip/hip_runtime.h>
#include <hip/hip_bf16.h>

// Problem constants
#define S_ 1024
#define B_ 8
#define D_ 256
#define H_ 8
#define DH_ 32
#define N_ 8192           // S*B nodes
#define E_ 262144
#define ET_ 270336        // E + N (self loops)

typedef unsigned short u16;
typedef float f32x4 __attribute__((ext_vector_type(4)));
typedef __bf16 bf16x8 __attribute__((ext_vector_type(8)));
typedef short s16x4 __attribute__((ext_vector_type(4)));

#define QK_SCALE 0.17677669529663687f  // 1/sqrt(32)

// f32 -> bf16 (RNE)
__device__ inline u16 f2bf(float v) {
    unsigned int u = __float_as_uint(v);
    u = (u + 0x7fffu + ((u >> 16) & 1u)) >> 16;
    return (u16)u;
}
__device__ inline float bf2f(u16 u) { return __uint_as_float(((unsigned int)u) << 16); }

// pack two f32 -> two bf16 (truncation) in one v_perm
__device__ inline unsigned int pack_trunc(float lo, float hi) {
    return __builtin_amdgcn_perm(__float_as_uint(hi), __float_as_uint(lo), 0x07060302u);
}

// async global->LDS 16B
__device__ inline void gload16(const u16* g, u16* l) {
    __builtin_amdgcn_global_load_lds((const __attribute__((address_space(1))) unsigned int*)g,
                                     (__attribute__((address_space(3))) unsigned int*)l, 16, 0, 0);
}

// K=16 bf16 MFMA
__device__ inline f32x4 mfma16bf(s16x4 a, s16x4 b, f32x4 c) {
#if __has_builtin(__builtin_amdgcn_mfma_f32_16x16x16bf16_1k)
    return __builtin_amdgcn_mfma_f32_16x16x16bf16_1k(a, b, c, 0, 0, 0);
#else
    asm volatile("v_mfma_f32_16x16x16_bf16 %0, %1, %2, %0" : "+v"(c) : "v"(a), "v"(b));
    return c;
#endif
}

// -------------------- fused conversions + zero-init of sort counters --------------------
__global__ __launch_bounds__(256) void convert_all(const float* __restrict__ x,  const float* __restrict__ wi,
                                                   const float* __restrict__ wo, const float* __restrict__ wl,
                                                   const float* __restrict__ w1, const float* __restrict__ w2,
                                                   u16* __restrict__ Xbf, u16* __restrict__ Wi, u16* __restrict__ Wo,
                                                   u16* __restrict__ Wl, u16* __restrict__ W1, u16* __restrict__ W2,
                                                   int* __restrict__ count, int* __restrict__ cursor)
{
    const int idx = blockIdx.x * 256 + threadIdx.x;
    const int C0 = 2097152;            // x   8192*256
    const int C1 = C0 + 196608;        // in_proj 768*256
    const int C2 = C1 + 65536;         // out_proj
    const int C3 = C2 + 65536;         // lin
    const int C4 = C3 + 294912;        // w1 padded 1024*288 (kin 257)
    const int C5 = C4 + 262144;        // w2 256*1024
    const int C6 = C5 + 16384;         // zero COUNT(8192) + CURSOR(8192)
    if (idx < C0)      { Xbf[idx] = f2bf(x[idx]); }
    else if (idx < C1) { int i = idx - C0; Wi[i] = f2bf(wi[i]); }
    else if (idx < C2) { int i = idx - C1; Wo[i] = f2bf(wo[i]); }
    else if (idx < C3) { int i = idx - C2; Wl[i] = f2bf(wl[i]); }
    else if (idx < C4) { int i = idx - C3; int r = i / 288, k = i - r * 288;
                         W1[i] = (k < 257) ? f2bf(w1[r * 257 + k]) : (u16)0; }
    else if (idx < C5) { int i = idx - C4; W2[i] = f2bf(w2[i]); }
    else if (idx < C6) { int i = idx - C5; if (i < 8192) count[i] = 0; else cursor[i - 8192] = 0; }
}

// -------------------- QKV GEMM (BN=64, QKV layout out) + edge histogram in extra blocks --------------------
__global__ __launch_bounds__(256) void gemm_qkv_hist(const u16* __restrict__ A,
                                                     const u16* __restrict__ W,
                                                     const float* __restrict__ bias,
                                                     u16* __restrict__ Cv,
                                                     const int* __restrict__ ei, int* __restrict__ count)
{
    const int tid = threadIdx.x;
    if (blockIdx.x >= 768) {               // histogram blocks (COUNT zeroed by convert_all)
        const int e = (blockIdx.x - 768) * 256 + tid;   // 1056*256 == ET_
        const int dst = (e < E_) ? ei[E_ + e] : e - E_;
        atomicAdd(&count[dst], 1);
        return;
    }
    __shared__ u16 As[2][128 * 32];
    __shared__ u16 Bs[2][64 * 32];
    const int m0 = (blockIdx.x / 12) * 128, n0 = (blockIdx.x % 12) * 64;
    const int lane = tid & 63, w = tid >> 6;
    const int wm = w >> 1, wn = w & 1;
    const int lr = lane & 15, lg = lane >> 4;

    f32x4 acc[4][2] = {};

    const u16* Ag = A + (size_t)(m0 + (tid >> 2)) * 256 + (tid & 3) * 8;
    const u16* Wg = W + (size_t)(n0 + (tid >> 2)) * 256 + (tid & 3) * 8;

    auto stage = [&](int buf, int k0) {
        gload16(Ag + k0,                    &As[buf][tid * 8]);
        gload16(Ag + (size_t)64 * 256 + k0, &As[buf][64 * 32 + tid * 8]);
        gload16(Wg + k0,                    &Bs[buf][tid * 8]);
    };
    stage(0, 0);
    __syncthreads();
    int cur = 0;
    for (int kt = 0; kt < 8; ++kt) {
        if (kt + 1 < 8) stage(cur ^ 1, (kt + 1) << 5);
        bf16x8 af[4], bg[2];
        #pragma unroll
        for (int i = 0; i < 4; ++i) af[i] = *(const bf16x8*)&As[cur][(wm * 64 + i * 16 + lr) * 32 + lg * 8];
        #pragma unroll
        for (int i = 0; i < 2; ++i) bg[i] = *(const bf16x8*)&Bs[cur][(wn * 32 + i * 16 + lr) * 32 + lg * 8];
        #pragma unroll
        for (int mi = 0; mi < 4; ++mi)
            #pragma unroll
            for (int ni = 0; ni < 2; ++ni)
                acc[mi][ni] = __builtin_amdgcn_mfma_f32_16x16x32_bf16(af[mi], bg[ni], acc[mi][ni], 0, 0, 0);
        __syncthreads();
        cur ^= 1;
    }
    #pragma unroll
    for (int mi = 0; mi < 4; ++mi)
        #pragma unroll
        for (int ni = 0; ni < 2; ++ni) {
            const int col = n0 + wn * 32 + ni * 16 + lr;
            const float bv = bias[col];
            const int part = col >> 8, hh = (col >> 5) & 7, dh = col & 31;
            #pragma unroll
            for (int r = 0; r < 4; ++r) {
                const int row = m0 + wm * 64 + mi * 16 + lg * 4 + r;
                const int ss = row >> 3, bb = row & 7;
                Cv[(((size_t)((part * 8 + bb) * 8 + hh)) * 1024 + ss) * 32 + dh] = f2bf(acc[mi][ni][r] + bv);
            }
        }
}

// -------------------- MFMA flash attention (double-buffered, no-max softmax) + offset scan --------------------
__global__ __launch_bounds__(512) void attn_mfma(const u16* __restrict__ qkv, u16* __restrict__ ctx,
                                                 const int* __restrict__ count, int* __restrict__ offset)
{
    const int tid = threadIdx.x;
    if (blockIdx.x == 512) {               // prefix-scan block (COUNT complete: previous dispatch)
        __shared__ int s[512];
        const int base = tid * 16;
        int c[16]; int sum = 0;
        #pragma unroll
        for (int i = 0; i < 16; ++i) { c[i] = count[base + i]; sum += c[i]; }
        s[tid] = sum; __syncthreads();
        for (int off = 1; off < 512; off <<= 1) {
            int add = (tid >= off) ? s[tid - off] : 0;
            __syncthreads();
            s[tid] += add;
            __syncthreads();
        }
        int run = (tid == 0) ? 0 : s[tid - 1];
        #pragma unroll
        for (int i = 0; i < 16; ++i) { offset[base + i] = run; run += c[i]; }
        if (tid == 511) offset[8192] = run;   // = ET_
        return;
    }
    const int qt = blockIdx.x & 7, bh = blockIdx.x >> 3;
    const int b = bh >> 3, h = bh & 7;
    const int lane = tid & 63, w = tid >> 6;
    const int c = lane & 15, g = lane >> 4;

    __shared__ __align__(16) u16 Ks[2][128][40];
    __shared__ __align__(16) u16 Vt[2][32][132];

    const size_t plane = (size_t)(b * 8 + h) * 32768;
    const int q0 = qt * 128 + w * 16;
    const bf16x8 qf = *(const bf16x8*)&qkv[plane + (size_t)(q0 + c) * 32 + g * 8];
    const u16* kbase = qkv + 2097152 + plane;

    auto stage = [&](int buf, int kt) {
        const int r = tid >> 2, c0 = (tid & 3) * 8;
        const u16* kp = kbase + (size_t)(kt * 128 + r) * 32 + c0;
        *(uint4*)&Ks[buf][r][c0] = *(const uint4*)kp;
        u16 vb[8];
        *(uint4*)vb = *(const uint4*)(kp + 2097152);
        #pragma unroll
        for (int i = 0; i < 8; ++i) Vt[buf][c0 + i][r] = vb[i];
    };

    float l = 0.f;
    f32x4 o0 = {}, o1 = {};

    stage(0, 0);
    __syncthreads();
    int cur = 0;
    for (int kt = 0; kt < 8; ++kt) {
        if (kt + 1 < 8) stage(cur ^ 1, kt + 1);
        f32x4 sc[8];
        #pragma unroll
        for (int t = 0; t < 8; ++t) {
            const bf16x8 kf = *(const bf16x8*)&Ks[cur][t * 16 + c][g * 8];
            sc[t] = __builtin_amdgcn_mfma_f32_16x16x32_bf16(kf, qf, (f32x4){0.f, 0.f, 0.f, 0.f}, 0, 0, 0);
        }
        unsigned int pb[8][2];
        float ls = 0.f;
        #pragma unroll
        for (int t = 0; t < 8; ++t) {
            const float p0 = __expf(sc[t][0] * QK_SCALE);
            const float p1 = __expf(sc[t][1] * QK_SCALE);
            const float p2 = __expf(sc[t][2] * QK_SCALE);
            const float p3 = __expf(sc[t][3] * QK_SCALE);
            ls += (p0 + p1) + (p2 + p3);
            pb[t][0] = pack_trunc(p0, p1);
            pb[t][1] = pack_trunc(p2, p3);
        }
        l += ls;
        #pragma unroll
        for (int t = 0; t < 8; ++t) {
            union { unsigned int u[2]; s16x4 v; } pu;
            pu.u[0] = pb[t][0]; pu.u[1] = pb[t][1];
            const s16x4 vf0 = *(const s16x4*)&Vt[cur][c][t * 16 + g * 4];
            const s16x4 vf1 = *(const s16x4*)&Vt[cur][16 + c][t * 16 + g * 4];
            o0 = mfma16bf(vf0, pu.v, o0);
            o1 = mfma16bf(vf1, pu.v, o1);
        }
        __syncthreads();
        cur ^= 1;
    }
    l += __shfl_xor(l, 16, 64);
    l += __shfl_xor(l, 32, 64);
    const float inv = 1.f / l;
    u16 ob[8];
    #pragma unroll
    for (int r = 0; r < 4; ++r) { ob[r] = f2bf(o0[r] * inv); ob[4 + r] = f2bf(o1[r] * inv); }
    const size_t obase = ((size_t)(q0 + c) * 8 + b) * 256 + h * 32 + g * 4;
    *(uint2*)&ctx[obase]      = *(uint2*)ob;
    *(uint2*)&ctx[obase + 16] = *(uint2*)(ob + 4);
}

// -------------------- fused GEMM + epilogue (BM=16, BN=256, 8 waves = 8 col-groups) --------------------
// Wave w owns cols w*32..w*32+31 (== head w for MODE 1). Grid 512 m-blocks -> 2 blocks/CU.
// MODE 0: +bias +resid -> LN -> outf f32 AND outn bf16 node-major; blocks >= 512 do edge scatter
// MODE 1: raw gemm -> outn bf16 + per-head att scores asrc/adst (rows are nodes)
// MODE 2: +bias +resid -> LN -> outf f32 only
template<int MODE>
__global__ __launch_bounds__(512) void gemm_ln(const u16* __restrict__ A, int lda,
                                               const u16* __restrict__ W, int ldw, int Ksz,
                                               const float* __restrict__ bias,
                                               const float* __restrict__ resid,
                                               const float* __restrict__ gamma,
                                               const float* __restrict__ beta,
                                               const float* __restrict__ att_s,
                                               const float* __restrict__ att_d,
                                               float* __restrict__ outf,
                                               u16* __restrict__ outn,
                                               float* __restrict__ asrc,
                                               float* __restrict__ adst,
                                               const int* __restrict__ ei,
                                               const int* __restrict__ offset,
                                               int* __restrict__ cursor,
                                               int* __restrict__ sorted)
{
    constexpr int BM = 16;
    const int tid = threadIdx.x;
    if (MODE == 0 && blockIdx.x >= 512) {  // scatter blocks (OFFSET ready: previous dispatch)
        const int e = (blockIdx.x - 512) * 512 + tid;   // 528*512 == ET_
        int src, dst;
        if (e < E_) { src = ei[e]; dst = ei[E_ + e]; }
        else        { src = dst = e - E_; }
        const int pos = offset[dst] + atomicAdd(&cursor[dst], 1);
        sorted[pos] = src;
        return;
    }
    __shared__ u16 As[2][BM * 32];
    __shared__ u16 Bs[2][256 * 32];
    __shared__ float2 red[BM][8];
    const int m0 = blockIdx.x * BM;
    const int lane = tid & 63, w = tid >> 6;   // w = col-group 0..7
    const int lr = lane & 15, lg = lane >> 4;

    f32x4 acc[2] = {};

    auto stage = [&](int buf, int k0) {
        #pragma unroll
        for (int j = 0; j < 2; ++j) {
            const int idx = tid + j * 512;
            gload16(W + (size_t)(idx >> 2) * ldw + (idx & 3) * 8 + k0, &Bs[buf][idx * 8]);
        }
        if (tid < BM * 4)
            gload16(A + (size_t)(m0 + (tid >> 2)) * lda + (tid & 3) * 8 + k0, &As[buf][tid * 8]);
    };
    stage(0, 0);
    __syncthreads();
    const int nt = Ksz >> 5;
    int cur = 0;
    for (int kt = 0; kt < nt; ++kt) {
        if (kt + 1 < nt) stage(cur ^ 1, (kt + 1) << 5);
        const bf16x8 af = *(const bf16x8*)&As[cur][lr * 32 + lg * 8];
        bf16x8 bg[2];
        #pragma unroll
        for (int i = 0; i < 2; ++i)
            bg[i] = *(const bf16x8*)&Bs[cur][(w * 32 + i * 16 + lr) * 32 + lg * 8];
        #pragma unroll
        for (int ni = 0; ni < 2; ++ni)
            acc[ni] = __builtin_amdgcn_mfma_f32_16x16x32_bf16(af, bg[ni], acc[ni], 0, 0, 0);
        __syncthreads();
        cur ^= 1;
    }
    // ---- epilogue ----
    int col[2]; float gam[2], bet[2], bv[2], asv[2], adv[2];
    #pragma unroll
    for (int ni = 0; ni < 2; ++ni) {
        col[ni] = w * 32 + ni * 16 + lr;
        if (MODE != 1) { gam[ni] = gamma[col[ni]]; bet[ni] = beta[col[ni]]; bv[ni] = bias[col[ni]]; }
        else           { asv[ni] = att_s[col[ni]]; adv[ni] = att_d[col[ni]]; }
    }
    #pragma unroll
    for (int r = 0; r < 4; ++r) {
        const int row = lg * 4 + r;
        const int grow = m0 + row;
        float s1 = 0.f, s2 = 0.f;
        float2 sp = {0.f, 0.f};
        #pragma unroll
        for (int ni = 0; ni < 2; ++ni) {
            float v = acc[ni][r];
            if (MODE != 1) v += bv[ni] + resid[(size_t)grow * 256 + col[ni]];
            acc[ni][r] = v;
            if (MODE == 1) { sp.x += v * asv[ni]; sp.y += v * adv[ni]; }
            else           { s1 += v; s2 += v * v; }
        }
        #pragma unroll
        for (int msk = 1; msk < 16; msk <<= 1) {
            if (MODE == 1) { sp.x += __shfl_xor(sp.x, msk, 64); sp.y += __shfl_xor(sp.y, msk, 64); }
            else           { s1 += __shfl_xor(s1, msk, 64); s2 += __shfl_xor(s2, msk, 64); }
        }
        if (lr == 0) {
            if (MODE == 1) red[row][w] = sp;
            else           red[row][w] = (float2){s1, s2};
        }
    }
    __syncthreads();
    if (MODE == 1) {
        #pragma unroll
        for (int r = 0; r < 4; ++r) {
            const int grow = m0 + lg * 4 + r;
            #pragma unroll
            for (int ni = 0; ni < 2; ++ni)
                outn[(size_t)grow * 256 + col[ni]] = f2bf(acc[ni][r]);
        }
        for (int idx = tid; idx < BM * 8; idx += 512) {
            const int row = idx >> 3, h = idx & 7;
            asrc[(size_t)(m0 + row) * 8 + h] = red[row][h].x;
            adst[(size_t)(m0 + row) * 8 + h] = red[row][h].y;
        }
    } else {
        #pragma unroll
        for (int r = 0; r < 4; ++r) {
            const int row = lg * 4 + r;
            const int grow = m0 + row;
            float ts1 = 0.f, ts2 = 0.f;
            #pragma unroll
            for (int j = 0; j < 8; ++j) { ts1 += red[row][j].x; ts2 += red[row][j].y; }
            const float mean = ts1 * (1.f / 256.f);
            const float var  = ts2 * (1.f / 256.f) - mean * mean;
            const float rs = rsqrtf(var + 1e-5f);
            #pragma unroll
            for (int ni = 0; ni < 2; ++ni) {
                const float o = (acc[ni][r] - mean) * rs * gam[ni] + bet[ni];
                outf[(size_t)grow * 256 + col[ni]] = o;
                if (MODE == 0) {
                    const int node = (grow & 7) * 1024 + (grow >> 3);
                    outn[(size_t)node * 256 + col[ni]] = f2bf(o);
                }
            }
        }
    }
}

// -------------------- GAT gather + residual + LN2: ONE block per dst, 8 edge-streams --------------------
// 256 thr = 8 groups of 32 lanes; group g takes edges beg+g, beg+g+8, ... Lane l32 owns dims 8*l32..+7.
// LDS merge of 8 partials; lanes 0-31 do residual + LN + outputs. Grid 8192 -> 32 blocks/CU of TLP.
__global__ __launch_bounds__(256) void gat_gather_ln(const int* __restrict__ sorted, const int* __restrict__ offset,
                                                     const float* __restrict__ asrc, const float* __restrict__ adst,
                                                     const u16* __restrict__ xh,
                                                     const float* __restrict__ X1f, const float* __restrict__ gb,
                                                     const float* __restrict__ g2, const float* __restrict__ be2,
                                                     const float* __restrict__ cond,
                                                     float* __restrict__ X2f, u16* __restrict__ X2pad)
{
    const int tid = threadIdx.x;
    const int dst = blockIdx.x;
    const int grp = tid >> 5, l32 = tid & 31;
    const int h = l32 >> 2;                    // head of dims 8*l32..+7
    const float ad = adst[dst * 8 + h];
    const int beg = offset[dst], end = offset[dst + 1];

    __shared__ float szs[8][8];                // [group][head]
    __shared__ __align__(16) float sa[8][32][8];

    float z = 0.f;
    float a[8] = {};
    for (int i = beg + grp; i < end; i += 8) {
        const int src = sorted[i];
        float e = asrc[src * 8 + h] + ad;
        e = fmaxf(e, 0.2f * e);
        const float p = __expf(e);
        z += p;
        const uint4 xv = *(const uint4*)&xh[(size_t)src * 256 + l32 * 8];
        a[0] += p * __uint_as_float(xv.x << 16);
        a[1] += p * __uint_as_float(xv.x & 0xffff0000u);
        a[2] += p * __uint_as_float(xv.y << 16);
        a[3] += p * __uint_as_float(xv.y & 0xffff0000u);
        a[4] += p * __uint_as_float(xv.z << 16);
        a[5] += p * __uint_as_float(xv.z & 0xffff0000u);
        a[6] += p * __uint_as_float(xv.w << 16);
        a[7] += p * __uint_as_float(xv.w & 0xffff0000u);
    }
    if ((l32 & 3) == 0) szs[grp][h] = z;
    *(f32x4*)&sa[grp][l32][0] = (f32x4){a[0], a[1], a[2], a[3]};
    *(f32x4*)&sa[grp][l32][4] = (f32x4){a[4], a[5], a[6], a[7]};
    __syncthreads();
    if (tid >= 32) return;
    // merge 8 partials
    float zt = 0.f;
    float at[8] = {};
    #pragma unroll
    for (int g = 0; g < 8; ++g) {
        zt += szs[g][h];
        const f32x4 m0 = *(const f32x4*)&sa[g][l32][0];
        const f32x4 m1 = *(const f32x4*)&sa[g][l32][4];
        #pragma unroll
        for (int j = 0; j < 4; ++j) { at[j] += m0[j]; at[4 + j] += m1[j]; }
    }
    const float inv = 1.f / zt;
    const int row = (dst & 1023) * 8 + (dst >> 10);    // dst = b*1024 + s -> row = s*8 + b
    float v[8];
    {
        const f32x4 x0 = *(const f32x4*)&X1f[(size_t)row * 256 + l32 * 8];
        const f32x4 x1 = *(const f32x4*)&X1f[(size_t)row * 256 + l32 * 8 + 4];
        const f32x4 gb0 = *(const f32x4*)&gb[l32 * 8];
        const f32x4 gb1 = *(const f32x4*)&gb[l32 * 8 + 4];
        #pragma unroll
        for (int j = 0; j < 4; ++j) {
            v[j]     = x0[j] + at[j] * inv + gb0[j];
            v[4 + j] = x1[j] + at[4 + j] * inv + gb1[j];
        }
    }
    float s1 = 0.f, s2 = 0.f;
    #pragma unroll
    for (int j = 0; j < 8; ++j) { s1 += v[j]; s2 += v[j] * v[j]; }
    #pragma unroll
    for (int msk = 1; msk < 32; msk <<= 1) { s1 += __shfl_xor(s1, msk, 64); s2 += __shfl_xor(s2, msk, 64); }
    const float mean = s1 * (1.f / 256.f);
    const float var = s2 * (1.f / 256.f) - mean * mean;
    const float rs = rsqrtf(var + 1e-5f);
    const f32x4 gg0 = *(const f32x4*)&g2[l32 * 8];
    const f32x4 gg1 = *(const f32x4*)&g2[l32 * 8 + 4];
    const f32x4 be0 = *(const f32x4*)&be2[l32 * 8];
    const f32x4 be1 = *(const f32x4*)&be2[l32 * 8 + 4];
    f32x4 o0, o1;
    u16 ob[8];
    #pragma unroll
    for (int j = 0; j < 4; ++j) {
        o0[j] = (v[j] - mean) * rs * gg0[j] + be0[j];
        o1[j] = (v[4 + j] - mean) * rs * gg1[j] + be1[j];
        ob[j] = f2bf(o0[j]); ob[4 + j] = f2bf(o1[j]);
    }
    *(f32x4*)&X2f[(size_t)row * 256 + l32 * 8]     = o0;
    *(f32x4*)&X2f[(size_t)row * 256 + l32 * 8 + 4] = o1;
    *(uint4*)&X2pad[(size_t)row * 288 + l32 * 8] = *(uint4*)ob;
    if (l32 < 8) {
        u16 zz[4] = {0, 0, 0, 0};
        if (l32 == 0) zz[0] = f2bf(cond[row]);
        *(uint2*)&X2pad[(size_t)row * 288 + 256 + l32 * 4] = *(uint2*)zz;
    }
}

// -------------------- FFN w1 GEMM (128x128 tile) --------------------
__global__ __launch_bounds__(256) void gemm_w1(const u16* __restrict__ A,
                                               const u16* __restrict__ W,
                                               const float* __restrict__ bias,
                                               u16* __restrict__ Cv)
{
    __shared__ u16 As[2][128 * 32];
    __shared__ u16 Bs[2][128 * 32];
    const int tid = threadIdx.x;
    const int m0 = blockIdx.y * 128, n0 = blockIdx.x * 128;
    const int lane = tid & 63, w = tid >> 6;
    const int wm = w >> 1, wn = w & 1;
    const int lr = lane & 15, lg = lane >> 4;

    f32x4 acc[4][4] = {};

    const u16* Ag = A + (size_t)(m0 + (tid >> 2)) * 288 + (tid & 3) * 8;
    const u16* Wg = W + (size_t)(n0 + (tid >> 2)) * 288 + (tid & 3) * 8;

    auto stage = [&](int buf, int k0) {
        gload16(Ag + k0,                    &As[buf][tid * 8]);
        gload16(Ag + (size_t)64 * 288 + k0, &As[buf][64 * 32 + tid * 8]);
        gload16(Wg + k0,                    &Bs[buf][tid * 8]);
        gload16(Wg + (size_t)64 * 288 + k0, &Bs[buf][64 * 32 + tid * 8]);
    };
    stage(0, 0);
    __syncthreads();
    int cur = 0;
    for (int kt = 0; kt < 9; ++kt) {
        if (kt + 1 < 9) stage(cur ^ 1, (kt + 1) << 5);
        bf16x8 af[4], bg[4];
        #pragma unroll
        for (int i = 0; i < 4; ++i) {
            af[i] = *(const bf16x8*)&As[cur][(wm * 64 + i * 16 + lr) * 32 + lg * 8];
            bg[i] = *(const bf16x8*)&Bs[cur][(wn * 64 + i * 16 + lr) * 32 + lg * 8];
        }
        #pragma unroll
        for (int mi = 0; mi < 4; ++mi)
            #pragma unroll
            for (int ni = 0; ni < 4; ++ni)
                acc[mi][ni] = __builtin_amdgcn_mfma_f32_16x16x32_bf16(af[mi], bg[ni], acc[mi][ni], 0, 0, 0);
        __syncthreads();
        cur ^= 1;
    }
    #pragma unroll
    for (int mi = 0; mi < 4; ++mi)
        #pragma unroll
        for (int ni = 0; ni < 4; ++ni) {
            const int col = n0 + wn * 64 + ni * 16 + lr;
            const float bv = bias[col];
            #pragma unroll
            for (int r = 0; r < 4; ++r) {
                const int row = m0 + wm * 64 + mi * 16 + lg * 4 + r;
                Cv[(size_t)row * 1024 + col] = f2bf(fmaxf(acc[mi][ni][r] + bv, 0.f));
            }
        }
}

extern "C" void kernel_launch(void* const* d_in, const int* in_sizes, int n_in,
                              void* d_out, int out_size, void* d_ws, size_t ws_size,
                              hipStream_t stream)
{
    const float* x          = (const float*)d_in[0];
    const float* condition  = (const float*)d_in[1];
    const float* in_proj_w  = (const float*)d_in[2];
    const float* in_proj_b  = (const float*)d_in[3];
    const float* out_proj_w = (const float*)d_in[4];
    const float* out_proj_b = (const float*)d_in[5];
    const float* g1         = (const float*)d_in[6];
    const float* be1        = (const float*)d_in[7];
    const float* g2         = (const float*)d_in[8];
    const float* be2        = (const float*)d_in[9];
    const float* g3         = (const float*)d_in[10];
    const float* be3        = (const float*)d_in[11];
    const float* lin_w      = (const float*)d_in[12];
    const float* att_src    = (const float*)d_in[13];
    const float* att_dst    = (const float*)d_in[14];
    const float* gat_bias   = (const float*)d_in[15];
    const float* w1         = (const float*)d_in[16];
    const float* bf1        = (const float*)d_in[17];
    const float* w2         = (const float*)d_in[18];
    const float* bf2        = (const float*)d_in[19];
    const int*   edge_index = (const int*)d_in[20];
    float* out = (float*)d_out;

    char* ws = (char*)d_ws;
    u16*   QKV    = (u16*)(ws + 0);              // 12.6MB [QKV gemm, attn]
    u16*   Hb     = (u16*)(ws + 0);              // 16MB   [w1 gemm, w2 gemm] (QKV dead)
    u16*   CTX    = (u16*)(ws + 16777216);       // 4MB    [attn, ln1-gemm]
    u16*   X1node = (u16*)(ws + 20971520);       // 4MB    [ln1-gemm, xh-gemm]
    u16*   XH     = (u16*)(ws + 25165824);       // 4MB    [xh-gemm, gather]
    float* X1f    = (float*)(ws + 29360128);     // 8MB    [ln1-gemm, gather]
    float* X2f    = (float*)(ws + 37748736);     // 8MB    [gather, w2-gemm]
    u16*   X2pad  = (u16*)(ws + 46137344);       // 4.72MB [gather, w1 gemm]
    u16*   Xbf    = (u16*)(ws + 50855936);       // 4MB    [convert, QKV gemm]
    float* ASRC   = (float*)(ws + 55050240);     // 256KB
    float* ADST   = (float*)(ws + 55312384);     // 256KB
    u16*   W_inp  = (u16*)(ws + 55574528);       // 393,216
    u16*   W_out  = (u16*)(ws + 55967744);       // 131,072
    u16*   W_lin  = (u16*)(ws + 56098816);       // 131,072
    u16*   W_w1   = (u16*)(ws + 56229888);       // 589,824 (1024 x 288)
    u16*   W_w2   = (u16*)(ws + 56819712);       // 524,288
    int*   COUNT  = (int*)(ws + 57344000);       // 32,768
    int*   OFFSET = (int*)(ws + 57376768);       // 36,864 (8193 used)
    int*   CURSOR = (int*)(ws + 57413632);       // 32,768
    int*   SORTED = (int*)(ws + 57446400);       // 1,081,344 -> ends 58,527,744

    // 1. conversions + zero sort counters
    convert_all<<<11712, 256, 0, stream>>>(x, in_proj_w, out_proj_w, lin_w, w1, w2,
                                           Xbf, W_inp, W_out, W_lin, W_w1, W_w2, COUNT, CURSOR);
    // 2. QKV GEMM (768 blocks) + edge histogram (1056 blocks)
    gemm_qkv_hist<<<1824, 256, 0, stream>>>(Xbf, W_inp, in_proj_b, QKV, edge_index, COUNT);
    // 3. flash attention (512 blocks, double-buffered, no-max softmax) + offset scan (1 block)
    attn_mfma<<<513, 512, 0, stream>>>(QKV, CTX, COUNT, OFFSET);
    // 4. X1 = LN(x + CTX@W_out^T + b) (512 blocks, BM=16) + edge scatter (528 blocks)
    gemm_ln<0><<<1040, 512, 0, stream>>>(CTX, 256, W_out, 256, 256, out_proj_b, x, g1, be1,
                                         nullptr, nullptr, X1f, X1node, nullptr, nullptr,
                                         edge_index, OFFSET, CURSOR, SORTED);
    // 5. XH = X1node @ W_lin^T + ASRC/ADST scores (512 blocks)
    gemm_ln<1><<<512, 512, 0, stream>>>(X1node, 256, W_lin, 256, 256, nullptr, nullptr, nullptr, nullptr,
                                        att_src, att_dst, nullptr, XH, ASRC, ADST,
                                        nullptr, nullptr, nullptr, nullptr);
    // 6. gather + residual + LN2 -> X2f f32 + X2pad bf16 (one block per dst)
    gat_gather_ln<<<8192, 256, 0, stream>>>(SORTED, OFFSET, ASRC, ADST, XH,
                                            X1f, gat_bias, g2, be2, condition, X2f, X2pad);
    // 7. H = relu(X2pad @ W_w1^T + bf1)
    gemm_w1<<<dim3(8, 64), 256, 0, stream>>>(X2pad, W_w1, bf1, Hb);
    // 8. out = LN(X2 + Hb@W_w2^T + bf2)  (512 blocks)
    gemm_ln<2><<<512, 512, 0, stream>>>(Hb, 1024, W_w2, 1024, 1024, bf2, X2f, g3, be3,
                                        nullptr, nullptr, out, nullptr, nullptr, nullptr,
                                        nullptr, nullptr, nullptr, nullptr);
}

// Round 16
// 136.980 us; speedup vs baseline: 1.0321x; 1.0321x over previous
//
#include <hip/hip_runtime.h>
#include <hip/hip_bf16.h>

// Problem constants
#define S_ 1024
#define B_ 8
#define D_ 256
#define H_ 8
#define DH_ 32
#define N_ 8192           // S*B nodes
#define E_ 262144
#define ET_ 270336        // E + N (self loops)

typedef unsigned short u16;
typedef float f32x4 __attribute__((ext_vector_type(4)));
typedef __bf16 bf16x8 __attribute__((ext_vector_type(8)));
typedef short s16x4 __attribute__((ext_vector_type(4)));

#define QK_SCALE 0.17677669529663687f  // 1/sqrt(32)

// f32 -> bf16 (RNE)
__device__ inline u16 f2bf(float v) {
    unsigned int u = __float_as_uint(v);
    u = (u + 0x7fffu + ((u >> 16) & 1u)) >> 16;
    return (u16)u;
}
__device__ inline float bf2f(u16 u) { return __uint_as_float(((unsigned int)u) << 16); }

// pack two f32 -> two bf16 (truncation) in one v_perm
__device__ inline unsigned int pack_trunc(float lo, float hi) {
    return __builtin_amdgcn_perm(__float_as_uint(hi), __float_as_uint(lo), 0x07060302u);
}

// async global->LDS 16B
__device__ inline void gload16(const u16* g, u16* l) {
    __builtin_amdgcn_global_load_lds((const __attribute__((address_space(1))) unsigned int*)g,
                                     (__attribute__((address_space(3))) unsigned int*)l, 16, 0, 0);
}

// K=16 bf16 MFMA
__device__ inline f32x4 mfma16bf(s16x4 a, s16x4 b, f32x4 c) {
#if __has_builtin(__builtin_amdgcn_mfma_f32_16x16x16bf16_1k)
    return __builtin_amdgcn_mfma_f32_16x16x16bf16_1k(a, b, c, 0, 0, 0);
#else
    asm volatile("v_mfma_f32_16x16x16_bf16 %0, %1, %2, %0" : "+v"(c) : "v"(a), "v"(b));
    return c;
#endif
}

// -------------------- fused conversions (x vectorized 4x) + zero-init of sort counters --------------------
__global__ __launch_bounds__(256) void convert_all(const float* __restrict__ x,  const float* __restrict__ wi,
                                                   const float* __restrict__ wo, const float* __restrict__ wl,
                                                   const float* __restrict__ w1, const float* __restrict__ w2,
                                                   u16* __restrict__ Xbf, u16* __restrict__ Wi, u16* __restrict__ Wo,
                                                   u16* __restrict__ Wl, u16* __restrict__ W1, u16* __restrict__ W2,
                                                   int* __restrict__ count, int* __restrict__ cursor)
{
    const int idx = blockIdx.x * 256 + threadIdx.x;
    const int C0 = 524288;             // x as float4 units: 8192*256/4
    const int C1 = C0 + 196608;        // in_proj 768*256
    const int C2 = C1 + 65536;         // out_proj
    const int C3 = C2 + 65536;         // lin
    const int C4 = C3 + 294912;        // w1 padded 1024*288 (kin 257)
    const int C5 = C4 + 262144;        // w2 256*1024
    const int C6 = C5 + 16384;         // zero COUNT(8192) + CURSOR(8192)
    if (idx < C0) {
        const float4 v = *(const float4*)&x[(size_t)idx * 4];
        u16 o[4] = {f2bf(v.x), f2bf(v.y), f2bf(v.z), f2bf(v.w)};
        *(uint2*)&Xbf[(size_t)idx * 4] = *(uint2*)o;
    }
    else if (idx < C1) { int i = idx - C0; Wi[i] = f2bf(wi[i]); }
    else if (idx < C2) { int i = idx - C1; Wo[i] = f2bf(wo[i]); }
    else if (idx < C3) { int i = idx - C2; Wl[i] = f2bf(wl[i]); }
    else if (idx < C4) { int i = idx - C3; int r = i / 288, k = i - r * 288;
                         W1[i] = (k < 257) ? f2bf(w1[r * 257 + k]) : (u16)0; }
    else if (idx < C5) { int i = idx - C4; W2[i] = f2bf(w2[i]); }
    else if (idx < C6) { int i = idx - C5; if (i < 8192) count[i] = 0; else cursor[i - 8192] = 0; }
}

// -------------------- QKV GEMM (BN=64, QKV layout out) + edge histogram in extra blocks --------------------
__global__ __launch_bounds__(256) void gemm_qkv_hist(const u16* __restrict__ A,
                                                     const u16* __restrict__ W,
                                                     const float* __restrict__ bias,
                                                     u16* __restrict__ Cv,
                                                     const int* __restrict__ ei, int* __restrict__ count)
{
    const int tid = threadIdx.x;
    if (blockIdx.x >= 768) {               // histogram blocks (COUNT zeroed by convert_all)
        const int e = (blockIdx.x - 768) * 256 + tid;   // 1056*256 == ET_
        const int dst = (e < E_) ? ei[E_ + e] : e - E_;
        atomicAdd(&count[dst], 1);
        return;
    }
    __shared__ u16 As[2][128 * 32];
    __shared__ u16 Bs[2][64 * 32];
    const int m0 = (blockIdx.x / 12) * 128, n0 = (blockIdx.x % 12) * 64;
    const int lane = tid & 63, w = tid >> 6;
    const int wm = w >> 1, wn = w & 1;
    const int lr = lane & 15, lg = lane >> 4;

    f32x4 acc[4][2] = {};

    const u16* Ag = A + (size_t)(m0 + (tid >> 2)) * 256 + (tid & 3) * 8;
    const u16* Wg = W + (size_t)(n0 + (tid >> 2)) * 256 + (tid & 3) * 8;

    auto stage = [&](int buf, int k0) {
        gload16(Ag + k0,                    &As[buf][tid * 8]);
        gload16(Ag + (size_t)64 * 256 + k0, &As[buf][64 * 32 + tid * 8]);
        gload16(Wg + k0,                    &Bs[buf][tid * 8]);
    };
    stage(0, 0);
    __syncthreads();
    int cur = 0;
    for (int kt = 0; kt < 8; ++kt) {
        if (kt + 1 < 8) stage(cur ^ 1, (kt + 1) << 5);
        bf16x8 af[4], bg[2];
        #pragma unroll
        for (int i = 0; i < 4; ++i) af[i] = *(const bf16x8*)&As[cur][(wm * 64 + i * 16 + lr) * 32 + lg * 8];
        #pragma unroll
        for (int i = 0; i < 2; ++i) bg[i] = *(const bf16x8*)&Bs[cur][(wn * 32 + i * 16 + lr) * 32 + lg * 8];
        #pragma unroll
        for (int mi = 0; mi < 4; ++mi)
            #pragma unroll
            for (int ni = 0; ni < 2; ++ni)
                acc[mi][ni] = __builtin_amdgcn_mfma_f32_16x16x32_bf16(af[mi], bg[ni], acc[mi][ni], 0, 0, 0);
        __syncthreads();
        cur ^= 1;
    }
    #pragma unroll
    for (int mi = 0; mi < 4; ++mi)
        #pragma unroll
        for (int ni = 0; ni < 2; ++ni) {
            const int col = n0 + wn * 32 + ni * 16 + lr;
            const float bv = bias[col];
            const int part = col >> 8, hh = (col >> 5) & 7, dh = col & 31;
            #pragma unroll
            for (int r = 0; r < 4; ++r) {
                const int row = m0 + wm * 64 + mi * 16 + lg * 4 + r;
                const int ss = row >> 3, bb = row & 7;
                Cv[(((size_t)((part * 8 + bb) * 8 + hh)) * 1024 + ss) * 32 + dh] = f2bf(acc[mi][ni][r] + bv);
            }
        }
}

// -------------------- MFMA flash attention (double-buffered, no-max softmax) + offset scan --------------------
__global__ __launch_bounds__(512) void attn_mfma(const u16* __restrict__ qkv, u16* __restrict__ ctx,
                                                 const int* __restrict__ count, int* __restrict__ offset)
{
    const int tid = threadIdx.x;
    if (blockIdx.x == 512) {               // prefix-scan block (COUNT complete: previous dispatch)
        __shared__ int s[512];
        const int base = tid * 16;
        int c[16]; int sum = 0;
        #pragma unroll
        for (int i = 0; i < 16; ++i) { c[i] = count[base + i]; sum += c[i]; }
        s[tid] = sum; __syncthreads();
        for (int off = 1; off < 512; off <<= 1) {
            int add = (tid >= off) ? s[tid - off] : 0;
            __syncthreads();
            s[tid] += add;
            __syncthreads();
        }
        int run = (tid == 0) ? 0 : s[tid - 1];
        #pragma unroll
        for (int i = 0; i < 16; ++i) { offset[base + i] = run; run += c[i]; }
        if (tid == 511) offset[8192] = run;   // = ET_
        return;
    }
    const int qt = blockIdx.x & 7, bh = blockIdx.x >> 3;
    const int b = bh >> 3, h = bh & 7;
    const int lane = tid & 63, w = tid >> 6;
    const int c = lane & 15, g = lane >> 4;

    __shared__ __align__(16) u16 Ks[2][128][40];
    __shared__ __align__(16) u16 Vt[2][32][132];

    const size_t plane = (size_t)(b * 8 + h) * 32768;
    const int q0 = qt * 128 + w * 16;
    const bf16x8 qf = *(const bf16x8*)&qkv[plane + (size_t)(q0 + c) * 32 + g * 8];
    const u16* kbase = qkv + 2097152 + plane;

    auto stage = [&](int buf, int kt) {
        const int r = tid >> 2, c0 = (tid & 3) * 8;
        const u16* kp = kbase + (size_t)(kt * 128 + r) * 32 + c0;
        *(uint4*)&Ks[buf][r][c0] = *(const uint4*)kp;
        u16 vb[8];
        *(uint4*)vb = *(const uint4*)(kp + 2097152);
        #pragma unroll
        for (int i = 0; i < 8; ++i) Vt[buf][c0 + i][r] = vb[i];
    };

    float l = 0.f;
    f32x4 o0 = {}, o1 = {};

    stage(0, 0);
    __syncthreads();
    int cur = 0;
    for (int kt = 0; kt < 8; ++kt) {
        if (kt + 1 < 8) stage(cur ^ 1, kt + 1);
        f32x4 sc[8];
        #pragma unroll
        for (int t = 0; t < 8; ++t) {
            const bf16x8 kf = *(const bf16x8*)&Ks[cur][t * 16 + c][g * 8];
            sc[t] = __builtin_amdgcn_mfma_f32_16x16x32_bf16(kf, qf, (f32x4){0.f, 0.f, 0.f, 0.f}, 0, 0, 0);
        }
        unsigned int pb[8][2];
        float ls = 0.f;
        #pragma unroll
        for (int t = 0; t < 8; ++t) {
            const float p0 = __expf(sc[t][0] * QK_SCALE);
            const float p1 = __expf(sc[t][1] * QK_SCALE);
            const float p2 = __expf(sc[t][2] * QK_SCALE);
            const float p3 = __expf(sc[t][3] * QK_SCALE);
            ls += (p0 + p1) + (p2 + p3);
            pb[t][0] = pack_trunc(p0, p1);
            pb[t][1] = pack_trunc(p2, p3);
        }
        l += ls;
        #pragma unroll
        for (int t = 0; t < 8; ++t) {
            union { unsigned int u[2]; s16x4 v; } pu;
            pu.u[0] = pb[t][0]; pu.u[1] = pb[t][1];
            const s16x4 vf0 = *(const s16x4*)&Vt[cur][c][t * 16 + g * 4];
            const s16x4 vf1 = *(const s16x4*)&Vt[cur][16 + c][t * 16 + g * 4];
            o0 = mfma16bf(vf0, pu.v, o0);
            o1 = mfma16bf(vf1, pu.v, o1);
        }
        __syncthreads();
        cur ^= 1;
    }
    l += __shfl_xor(l, 16, 64);
    l += __shfl_xor(l, 32, 64);
    const float inv = 1.f / l;
    u16 ob[8];
    #pragma unroll
    for (int r = 0; r < 4; ++r) { ob[r] = f2bf(o0[r] * inv); ob[4 + r] = f2bf(o1[r] * inv); }
    const size_t obase = ((size_t)(q0 + c) * 8 + b) * 256 + h * 32 + g * 4;
    *(uint2*)&ctx[obase]      = *(uint2*)ob;
    *(uint2*)&ctx[obase + 16] = *(uint2*)(ob + 4);
}

// -------------------- fused GEMM + epilogue (BM=32, BN=256 full row, 8 waves 2x4) --------------------
// MODE 0: +bias +resid -> LN -> outf f32 AND outn bf16 node-major; extra blocks (>=256) do edge scatter
// MODE 1: raw gemm -> outn bf16 + per-head att scores asrc/adst (rows are nodes)
// MODE 2: +bias +resid -> LN -> outf f32 only
template<int MODE>
__global__ __launch_bounds__(512) void gemm_ln(const u16* __restrict__ A, int lda,
                                               const u16* __restrict__ W, int ldw, int Ksz,
                                               const float* __restrict__ bias,
                                               const float* __restrict__ resid,
                                               const float* __restrict__ gamma,
                                               const float* __restrict__ beta,
                                               const float* __restrict__ att_s,
                                               const float* __restrict__ att_d,
                                               float* __restrict__ outf,
                                               u16* __restrict__ outn,
                                               float* __restrict__ asrc,
                                               float* __restrict__ adst,
                                               const int* __restrict__ ei,
                                               const int* __restrict__ offset,
                                               int* __restrict__ cursor,
                                               int* __restrict__ sorted)
{
    constexpr int BM = 32;
    const int tid = threadIdx.x;
    if (MODE == 0 && blockIdx.x >= 256) {  // scatter blocks (OFFSET ready: previous dispatch)
        const int e = (blockIdx.x - 256) * 512 + tid;   // 528*512 == ET_
        int src, dst;
        if (e < E_) { src = ei[e]; dst = ei[E_ + e]; }
        else        { src = dst = e - E_; }
        const int pos = offset[dst] + atomicAdd(&cursor[dst], 1);
        sorted[pos] = src;
        return;
    }
    __shared__ u16 As[2][BM * 32];
    __shared__ u16 Bs[2][256 * 32];
    __shared__ float2 red[BM][8];
    const int m0 = blockIdx.x * BM;
    const int lane = tid & 63, w = tid >> 6;
    const int rw = w >> 2, cw = w & 3;
    const int lr = lane & 15, lg = lane >> 4;

    f32x4 acc[4] = {};

    auto stage = [&](int buf, int k0) {
        #pragma unroll
        for (int j = 0; j < 2; ++j) {
            const int idx = tid + j * 512;
            gload16(W + (size_t)(idx >> 2) * ldw + (idx & 3) * 8 + k0, &Bs[buf][idx * 8]);
        }
        if (tid < BM * 4)
            gload16(A + (size_t)(m0 + (tid >> 2)) * lda + (tid & 3) * 8 + k0, &As[buf][tid * 8]);
    };
    stage(0, 0);
    __syncthreads();
    const int nt = Ksz >> 5;
    int cur = 0;
    for (int kt = 0; kt < nt; ++kt) {
        if (kt + 1 < nt) stage(cur ^ 1, (kt + 1) << 5);
        bf16x8 af = *(const bf16x8*)&As[cur][(rw * 16 + lr) * 32 + lg * 8];
        bf16x8 bg[4];
        #pragma unroll
        for (int i = 0; i < 4; ++i)  bg[i] = *(const bf16x8*)&Bs[cur][(cw * 64 + i * 16 + lr) * 32 + lg * 8];
        #pragma unroll
        for (int ni = 0; ni < 4; ++ni)
            acc[ni] = __builtin_amdgcn_mfma_f32_16x16x32_bf16(af, bg[ni], acc[ni], 0, 0, 0);
        __syncthreads();
        cur ^= 1;
    }
    // ---- epilogue ----
    int col[4]; float gam[4], bet[4], bv[4], asv[4], adv[4];
    #pragma unroll
    for (int ni = 0; ni < 4; ++ni) {
        col[ni] = cw * 64 + ni * 16 + lr;
        if (MODE != 1) { gam[ni] = gamma[col[ni]]; bet[ni] = beta[col[ni]]; bv[ni] = bias[col[ni]]; }
        else           { asv[ni] = att_s[col[ni]]; adv[ni] = att_d[col[ni]]; }
    }
    #pragma unroll
    for (int r = 0; r < 4; ++r) {
        const int row = rw * 16 + lg * 4 + r;
        const int grow = m0 + row;
        float s1 = 0.f, s2 = 0.f;
        float2 sp0 = {0.f, 0.f}, sp1 = {0.f, 0.f};
        #pragma unroll
        for (int ni = 0; ni < 4; ++ni) {
            float v = acc[ni][r];
            if (MODE != 1) v += bv[ni] + resid[(size_t)grow * 256 + col[ni]];
            acc[ni][r] = v;
            if (MODE == 1) {
                if (ni < 2) { sp0.x += v * asv[ni]; sp0.y += v * adv[ni]; }
                else        { sp1.x += v * asv[ni]; sp1.y += v * adv[ni]; }
            } else { s1 += v; s2 += v * v; }
        }
        #pragma unroll
        for (int msk = 1; msk < 16; msk <<= 1) {
            if (MODE == 1) {
                sp0.x += __shfl_xor(sp0.x, msk, 64); sp0.y += __shfl_xor(sp0.y, msk, 64);
                sp1.x += __shfl_xor(sp1.x, msk, 64); sp1.y += __shfl_xor(sp1.y, msk, 64);
            } else { s1 += __shfl_xor(s1, msk, 64); s2 += __shfl_xor(s2, msk, 64); }
        }
        if (lr == 0) {
            if (MODE == 1) { red[row][cw * 2] = sp0; red[row][cw * 2 + 1] = sp1; }
            else           { red[row][cw] = (float2){s1, s2}; }
        }
    }
    __syncthreads();
    if (MODE == 1) {
        #pragma unroll
        for (int r = 0; r < 4; ++r) {
            const int grow = m0 + rw * 16 + lg * 4 + r;
            #pragma unroll
            for (int ni = 0; ni < 4; ++ni)
                outn[(size_t)grow * 256 + col[ni]] = f2bf(acc[ni][r]);
        }
        for (int idx = tid; idx < BM * 8; idx += 512) {
            const int row = idx >> 3, h = idx & 7;
            asrc[(size_t)(m0 + row) * 8 + h] = red[row][h].x;
            adst[(size_t)(m0 + row) * 8 + h] = red[row][h].y;
        }
    } else {
        #pragma unroll
        for (int r = 0; r < 4; ++r) {
            const int row = rw * 16 + lg * 4 + r;
            const int grow = m0 + row;
            const float2 t0 = red[row][0], t1 = red[row][1], t2 = red[row][2], t3 = red[row][3];
            const float mean = (t0.x + t1.x + t2.x + t3.x) * (1.f / 256.f);
            const float var  = (t0.y + t1.y + t2.y + t3.y) * (1.f / 256.f) - mean * mean;
            const float rs = rsqrtf(var + 1e-5f);
            #pragma unroll
            for (int ni = 0; ni < 4; ++ni) {
                const float o = (acc[ni][r] - mean) * rs * gam[ni] + bet[ni];
                outf[(size_t)grow * 256 + col[ni]] = o;
                if (MODE == 0) {
                    const int node = (grow & 7) * 1024 + (grow >> 3);
                    outn[(size_t)node * 256 + col[ni]] = f2bf(o);
                }
            }
        }
    }
}

// -------------------- GAT gather + residual + LN2: 2 waves/dst, dual-edge lane split, no max --------------------
__global__ __launch_bounds__(256) void gat_gather_ln(const int* __restrict__ sorted, const int* __restrict__ offset,
                                                     const float* __restrict__ asrc, const float* __restrict__ adst,
                                                     const u16* __restrict__ xh,
                                                     const float* __restrict__ X1f, const float* __restrict__ gb,
                                                     const float* __restrict__ g2, const float* __restrict__ be2,
                                                     const float* __restrict__ cond,
                                                     float* __restrict__ X2f, u16* __restrict__ X2pad)
{
    const int wid = threadIdx.x >> 6, lane = threadIdx.x & 63;
    const int pair = wid >> 1, half = wid & 1;
    const int dst = blockIdx.x * 2 + pair;
    const int sub = lane >> 5, l32 = lane & 31;
    const int h = l32 >> 2;                     // head of dims 8*l32..+7
    const float ad = adst[dst * 8 + h];
    const int beg = offset[dst], end = offset[dst + 1];
    const int mid = beg + ((end - beg + 1) >> 1);
    const int b0 = half ? mid : beg;
    const int b1 = half ? end : mid;

    __shared__ float szs[2][8];
    __shared__ __align__(16) float sa[2][32][8];

    float z = 0.f;
    float a[8] = {};
    #pragma unroll 2
    for (int i = b0 + sub; i < b1; i += 2) {
        const int src = sorted[i];
        float e = asrc[src * 8 + h] + ad;
        e = fmaxf(e, 0.2f * e);
        const float p = __expf(e);
        z += p;
        const uint4 xv = *(const uint4*)&xh[(size_t)src * 256 + l32 * 8];
        a[0] += p * __uint_as_float(xv.x << 16);
        a[1] += p * __uint_as_float(xv.x & 0xffff0000u);
        a[2] += p * __uint_as_float(xv.y << 16);
        a[3] += p * __uint_as_float(xv.y & 0xffff0000u);
        a[4] += p * __uint_as_float(xv.z << 16);
        a[5] += p * __uint_as_float(xv.z & 0xffff0000u);
        a[6] += p * __uint_as_float(xv.w << 16);
        a[7] += p * __uint_as_float(xv.w & 0xffff0000u);
    }
    // combine the two 32-lane sub-halves
    z += __shfl_xor(z, 32, 64);
    #pragma unroll
    for (int j = 0; j < 8; ++j) a[j] += __shfl_xor(a[j], 32, 64);
    // cross-wave merge (half 1 -> LDS)
    if (half && sub == 0) {
        if ((l32 & 3) == 0) szs[pair][h] = z;
        *(f32x4*)&sa[pair][l32][0] = (f32x4){a[0], a[1], a[2], a[3]};
        *(f32x4*)&sa[pair][l32][4] = (f32x4){a[4], a[5], a[6], a[7]};
    }
    __syncthreads();
    if (half) return;
    const float zt = z + szs[pair][h];
    const float inv = 1.f / zt;
    const int row = (dst & 1023) * 8 + (dst >> 10);    // dst = b*1024 + s -> row = s*8 + b
    float v[8];
    {
        const f32x4 x0 = *(const f32x4*)&X1f[(size_t)row * 256 + l32 * 8];
        const f32x4 x1 = *(const f32x4*)&X1f[(size_t)row * 256 + l32 * 8 + 4];
        const f32x4 gb0 = *(const f32x4*)&gb[l32 * 8];
        const f32x4 gb1 = *(const f32x4*)&gb[l32 * 8 + 4];
        const f32x4 m0 = *(const f32x4*)&sa[pair][l32][0];
        const f32x4 m1 = *(const f32x4*)&sa[pair][l32][4];
        #pragma unroll
        for (int j = 0; j < 4; ++j) {
            v[j]     = x0[j] + (a[j] + m0[j]) * inv + gb0[j];
            v[4 + j] = x1[j] + (a[4 + j] + m1[j]) * inv + gb1[j];
        }
    }
    float s1 = 0.f, s2 = 0.f;
    #pragma unroll
    for (int j = 0; j < 8; ++j) { s1 += v[j]; s2 += v[j] * v[j]; }
    #pragma unroll
    for (int msk = 1; msk < 32; msk <<= 1) { s1 += __shfl_xor(s1, msk, 64); s2 += __shfl_xor(s2, msk, 64); }
    const float mean = s1 * (1.f / 256.f);
    const float var = s2 * (1.f / 256.f) - mean * mean;
    const float rs = rsqrtf(var + 1e-5f);
    if (sub == 0) {
        const f32x4 gg0 = *(const f32x4*)&g2[l32 * 8];
        const f32x4 gg1 = *(const f32x4*)&g2[l32 * 8 + 4];
        const f32x4 be0 = *(const f32x4*)&be2[l32 * 8];
        const f32x4 be1 = *(const f32x4*)&be2[l32 * 8 + 4];
        f32x4 o0, o1;
        u16 ob[8];
        #pragma unroll
        for (int j = 0; j < 4; ++j) {
            o0[j] = (v[j] - mean) * rs * gg0[j] + be0[j];
            o1[j] = (v[4 + j] - mean) * rs * gg1[j] + be1[j];
            ob[j] = f2bf(o0[j]); ob[4 + j] = f2bf(o1[j]);
        }
        *(f32x4*)&X2f[(size_t)row * 256 + l32 * 8]     = o0;
        *(f32x4*)&X2f[(size_t)row * 256 + l32 * 8 + 4] = o1;
        *(uint4*)&X2pad[(size_t)row * 288 + l32 * 8] = *(uint4*)ob;
        if (l32 < 8) {
            u16 zz[4] = {0, 0, 0, 0};
            if (l32 == 0) zz[0] = f2bf(cond[row]);
            *(uint2*)&X2pad[(size_t)row * 288 + 256 + l32 * 4] = *(uint2*)zz;
        }
    }
}

// -------------------- FFN w1 GEMM (128x128 tile) --------------------
__global__ __launch_bounds__(256) void gemm_w1(const u16* __restrict__ A,
                                               const u16* __restrict__ W,
                                               const float* __restrict__ bias,
                                               u16* __restrict__ Cv)
{
    __shared__ u16 As[2][128 * 32];
    __shared__ u16 Bs[2][128 * 32];
    const int tid = threadIdx.x;
    const int m0 = blockIdx.y * 128, n0 = blockIdx.x * 128;
    const int lane = tid & 63, w = tid >> 6;
    const int wm = w >> 1, wn = w & 1;
    const int lr = lane & 15, lg = lane >> 4;

    f32x4 acc[4][4] = {};

    const u16* Ag = A + (size_t)(m0 + (tid >> 2)) * 288 + (tid & 3) * 8;
    const u16* Wg = W + (size_t)(n0 + (tid >> 2)) * 288 + (tid & 3) * 8;

    auto stage = [&](int buf, int k0) {
        gload16(Ag + k0,                    &As[buf][tid * 8]);
        gload16(Ag + (size_t)64 * 288 + k0, &As[buf][64 * 32 + tid * 8]);
        gload16(Wg + k0,                    &Bs[buf][tid * 8]);
        gload16(Wg + (size_t)64 * 288 + k0, &Bs[buf][64 * 32 + tid * 8]);
    };
    stage(0, 0);
    __syncthreads();
    int cur = 0;
    for (int kt = 0; kt < 9; ++kt) {
        if (kt + 1 < 9) stage(cur ^ 1, (kt + 1) << 5);
        bf16x8 af[4], bg[4];
        #pragma unroll
        for (int i = 0; i < 4; ++i) {
            af[i] = *(const bf16x8*)&As[cur][(wm * 64 + i * 16 + lr) * 32 + lg * 8];
            bg[i] = *(const bf16x8*)&Bs[cur][(wn * 64 + i * 16 + lr) * 32 + lg * 8];
        }
        #pragma unroll
        for (int mi = 0; mi < 4; ++mi)
            #pragma unroll
            for (int ni = 0; ni < 4; ++ni)
                acc[mi][ni] = __builtin_amdgcn_mfma_f32_16x16x32_bf16(af[mi], bg[ni], acc[mi][ni], 0, 0, 0);
        __syncthreads();
        cur ^= 1;
    }
    #pragma unroll
    for (int mi = 0; mi < 4; ++mi)
        #pragma unroll
        for (int ni = 0; ni < 4; ++ni) {
            const int col = n0 + wn * 64 + ni * 16 + lr;
            const float bv = bias[col];
            #pragma unroll
            for (int r = 0; r < 4; ++r) {
                const int row = m0 + wm * 64 + mi * 16 + lg * 4 + r;
                Cv[(size_t)row * 1024 + col] = f2bf(fmaxf(acc[mi][ni][r] + bv, 0.f));
            }
        }
}

extern "C" void kernel_launch(void* const* d_in, const int* in_sizes, int n_in,
                              void* d_out, int out_size, void* d_ws, size_t ws_size,
                              hipStream_t stream)
{
    const float* x          = (const float*)d_in[0];
    const float* condition  = (const float*)d_in[1];
    const float* in_proj_w  = (const float*)d_in[2];
    const float* in_proj_b  = (const float*)d_in[3];
    const float* out_proj_w = (const float*)d_in[4];
    const float* out_proj_b = (const float*)d_in[5];
    const float* g1         = (const float*)d_in[6];
    const float* be1        = (const float*)d_in[7];
    const float* g2         = (const float*)d_in[8];
    const float* be2        = (const float*)d_in[9];
    const float* g3         = (const float*)d_in[10];
    const float* be3        = (const float*)d_in[11];
    const float* lin_w      = (const float*)d_in[12];
    const float* att_src    = (const float*)d_in[13];
    const float* att_dst    = (const float*)d_in[14];
    const float* gat_bias   = (const float*)d_in[15];
    const float* w1         = (const float*)d_in[16];
    const float* bf1        = (const float*)d_in[17];
    const float* w2         = (const float*)d_in[18];
    const float* bf2        = (const float*)d_in[19];
    const int*   edge_index = (const int*)d_in[20];
    float* out = (float*)d_out;

    char* ws = (char*)d_ws;
    u16*   QKV    = (u16*)(ws + 0);              // 12.6MB [QKV gemm, attn]
    u16*   Hb     = (u16*)(ws + 0);              // 16MB   [w1 gemm, w2 gemm] (QKV dead)
    u16*   CTX    = (u16*)(ws + 16777216);       // 4MB    [attn, ln1-gemm]
    u16*   X1node = (u16*)(ws + 20971520);       // 4MB    [ln1-gemm, xh-gemm]
    u16*   XH     = (u16*)(ws + 25165824);       // 4MB    [xh-gemm, gather]
    float* X1f    = (float*)(ws + 29360128);     // 8MB    [ln1-gemm, gather]
    float* X2f    = (float*)(ws + 37748736);     // 8MB    [gather, w2-gemm]
    u16*   X2pad  = (u16*)(ws + 46137344);       // 4.72MB [gather, w1 gemm]
    u16*   Xbf    = (u16*)(ws + 50855936);       // 4MB    [convert, QKV gemm]
    float* ASRC   = (float*)(ws + 55050240);     // 256KB
    float* ADST   = (float*)(ws + 55312384);     // 256KB
    u16*   W_inp  = (u16*)(ws + 55574528);       // 393,216
    u16*   W_out  = (u16*)(ws + 55967744);       // 131,072
    u16*   W_lin  = (u16*)(ws + 56098816);       // 131,072
    u16*   W_w1   = (u16*)(ws + 56229888);       // 589,824 (1024 x 288)
    u16*   W_w2   = (u16*)(ws + 56819712);       // 524,288
    int*   COUNT  = (int*)(ws + 57344000);       // 32,768
    int*   OFFSET = (int*)(ws + 57376768);       // 36,864 (8193 used)
    int*   CURSOR = (int*)(ws + 57413632);       // 32,768
    int*   SORTED = (int*)(ws + 57446400);       // 1,081,344 -> ends 58,527,744

    // 1. conversions (x vectorized) + zero sort counters
    convert_all<<<5568, 256, 0, stream>>>(x, in_proj_w, out_proj_w, lin_w, w1, w2,
                                          Xbf, W_inp, W_out, W_lin, W_w1, W_w2, COUNT, CURSOR);
    // 2. QKV GEMM (768 blocks) + edge histogram (1056 blocks)
    gemm_qkv_hist<<<1824, 256, 0, stream>>>(Xbf, W_inp, in_proj_b, QKV, edge_index, COUNT);
    // 3. flash attention (512 blocks, double-buffered, no-max softmax) + offset scan (1 block)
    attn_mfma<<<513, 512, 0, stream>>>(QKV, CTX, COUNT, OFFSET);
    // 4. X1 = LN(x + CTX@W_out^T + b) (256 blocks) + edge scatter (528 blocks)
    gemm_ln<0><<<784, 512, 0, stream>>>(CTX, 256, W_out, 256, 256, out_proj_b, x, g1, be1,
                                        nullptr, nullptr, X1f, X1node, nullptr, nullptr,
                                        edge_index, OFFSET, CURSOR, SORTED);
    // 5. XH = X1node @ W_lin^T + ASRC/ADST scores (256 blocks)
    gemm_ln<1><<<256, 512, 0, stream>>>(X1node, 256, W_lin, 256, 256, nullptr, nullptr, nullptr, nullptr,
                                        att_src, att_dst, nullptr, XH, ASRC, ADST,
                                        nullptr, nullptr, nullptr, nullptr);
    // 6. gather + residual + LN2 -> X2f f32 + X2pad bf16 (K=288 w/ cond col)
    gat_gather_ln<<<4096, 256, 0, stream>>>(SORTED, OFFSET, ASRC, ADST, XH,
                                            X1f, gat_bias, g2, be2, condition, X2f, X2pad);
    // 7. H = relu(X2pad @ W_w1^T + bf1)
    gemm_w1<<<dim3(8, 64), 256, 0, stream>>>(X2pad, W_w1, bf1, Hb);
    // 8. out = LN(X2 + Hb@W_w2^T + bf2)
    gemm_ln<2><<<256, 512, 0, stream>>>(Hb, 1024, W_w2, 1024, 1024, bf2, X2f, g3, be3,
                                        nullptr, nullptr, out, nullptr, nullptr, nullptr,
                                        nullptr, nullptr, nullptr, nullptr);
}

// Round 17
// 133.778 us; speedup vs baseline: 1.0568x; 1.0239x over previous
//
#include <hip/hip_runtime.h>
#include <hip/hip_bf16.h>

// Problem constants
#define S_ 1024
#define B_ 8
#define D_ 256
#define H_ 8
#define DH_ 32
#define N_ 8192           // S*B nodes
#define E_ 262144
#define ET_ 270336        // E + N (self loops)

typedef unsigned short u16;
typedef float f32x4 __attribute__((ext_vector_type(4)));
typedef __bf16 bf16x8 __attribute__((ext_vector_type(8)));
typedef short s16x4 __attribute__((ext_vector_type(4)));

#define QK_SCALE 0.17677669529663687f  // 1/sqrt(32)

// f32 -> bf16 (RNE)
__device__ inline u16 f2bf(float v) {
    unsigned int u = __float_as_uint(v);
    u = (u + 0x7fffu + ((u >> 16) & 1u)) >> 16;
    return (u16)u;
}
__device__ inline float bf2f(u16 u) { return __uint_as_float(((unsigned int)u) << 16); }

// pack two f32 -> two bf16 (truncation) in one v_perm
__device__ inline unsigned int pack_trunc(float lo, float hi) {
    return __builtin_amdgcn_perm(__float_as_uint(hi), __float_as_uint(lo), 0x07060302u);
}

// async global->LDS 16B
__device__ inline void gload16(const u16* g, u16* l) {
    __builtin_amdgcn_global_load_lds((const __attribute__((address_space(1))) unsigned int*)g,
                                     (__attribute__((address_space(3))) unsigned int*)l, 16, 0, 0);
}

// K=16 bf16 MFMA
__device__ inline f32x4 mfma16bf(s16x4 a, s16x4 b, f32x4 c) {
#if __has_builtin(__builtin_amdgcn_mfma_f32_16x16x16bf16_1k)
    return __builtin_amdgcn_mfma_f32_16x16x16bf16_1k(a, b, c, 0, 0, 0);
#else
    asm volatile("v_mfma_f32_16x16x16_bf16 %0, %1, %2, %0" : "+v"(c) : "v"(a), "v"(b));
    return c;
#endif
}

// -------------------- fused conversions (x vectorized 4x) + zero-init of sort counters --------------------
__global__ __launch_bounds__(256) void convert_all(const float* __restrict__ x,  const float* __restrict__ wi,
                                                   const float* __restrict__ wo, const float* __restrict__ wl,
                                                   const float* __restrict__ w1, const float* __restrict__ w2,
                                                   u16* __restrict__ Xbf, u16* __restrict__ Wi, u16* __restrict__ Wo,
                                                   u16* __restrict__ Wl, u16* __restrict__ W1, u16* __restrict__ W2,
                                                   int* __restrict__ count, int* __restrict__ cursor)
{
    const int idx = blockIdx.x * 256 + threadIdx.x;
    const int C0 = 524288;             // x as float4 units: 8192*256/4
    const int C1 = C0 + 196608;        // in_proj 768*256
    const int C2 = C1 + 65536;         // out_proj
    const int C3 = C2 + 65536;         // lin
    const int C4 = C3 + 294912;        // w1 padded 1024*288 (kin 257)
    const int C5 = C4 + 262144;        // w2 256*1024
    const int C6 = C5 + 16384;         // zero COUNT(8192) + CURSOR(8192)
    if (idx < C0) {
        const float4 v = *(const float4*)&x[(size_t)idx * 4];
        u16 o[4] = {f2bf(v.x), f2bf(v.y), f2bf(v.z), f2bf(v.w)};
        *(uint2*)&Xbf[(size_t)idx * 4] = *(uint2*)o;
    }
    else if (idx < C1) { int i = idx - C0; Wi[i] = f2bf(wi[i]); }
    else if (idx < C2) { int i = idx - C1; Wo[i] = f2bf(wo[i]); }
    else if (idx < C3) { int i = idx - C2; Wl[i] = f2bf(wl[i]); }
    else if (idx < C4) { int i = idx - C3; int r = i / 288, k = i - r * 288;
                         W1[i] = (k < 257) ? f2bf(w1[r * 257 + k]) : (u16)0; }
    else if (idx < C5) { int i = idx - C4; W2[i] = f2bf(w2[i]); }
    else if (idx < C6) { int i = idx - C5; if (i < 8192) count[i] = 0; else cursor[i - 8192] = 0; }
}

// -------------------- QKV GEMM (BN=64, QKV layout out) + edge histogram in extra blocks --------------------
__global__ __launch_bounds__(256) void gemm_qkv_hist(const u16* __restrict__ A,
                                                     const u16* __restrict__ W,
                                                     const float* __restrict__ bias,
                                                     u16* __restrict__ Cv,
                                                     const int* __restrict__ ei, int* __restrict__ count)
{
    const int tid = threadIdx.x;
    if (blockIdx.x >= 768) {               // histogram blocks (COUNT zeroed by convert_all)
        const int e = (blockIdx.x - 768) * 256 + tid;   // 1056*256 == ET_
        const int dst = (e < E_) ? ei[E_ + e] : e - E_;
        atomicAdd(&count[dst], 1);
        return;
    }
    __shared__ u16 As[2][128 * 32];
    __shared__ u16 Bs[2][64 * 32];
    const int m0 = (blockIdx.x / 12) * 128, n0 = (blockIdx.x % 12) * 64;
    const int lane = tid & 63, w = tid >> 6;
    const int wm = w >> 1, wn = w & 1;
    const int lr = lane & 15, lg = lane >> 4;

    f32x4 acc[4][2] = {};

    const u16* Ag = A + (size_t)(m0 + (tid >> 2)) * 256 + (tid & 3) * 8;
    const u16* Wg = W + (size_t)(n0 + (tid >> 2)) * 256 + (tid & 3) * 8;

    auto stage = [&](int buf, int k0) {
        gload16(Ag + k0,                    &As[buf][tid * 8]);
        gload16(Ag + (size_t)64 * 256 + k0, &As[buf][64 * 32 + tid * 8]);
        gload16(Wg + k0,                    &Bs[buf][tid * 8]);
    };
    stage(0, 0);
    __syncthreads();
    int cur = 0;
    for (int kt = 0; kt < 8; ++kt) {
        if (kt + 1 < 8) stage(cur ^ 1, (kt + 1) << 5);
        bf16x8 af[4], bg[2];
        #pragma unroll
        for (int i = 0; i < 4; ++i) af[i] = *(const bf16x8*)&As[cur][(wm * 64 + i * 16 + lr) * 32 + lg * 8];
        #pragma unroll
        for (int i = 0; i < 2; ++i) bg[i] = *(const bf16x8*)&Bs[cur][(wn * 32 + i * 16 + lr) * 32 + lg * 8];
        #pragma unroll
        for (int mi = 0; mi < 4; ++mi)
            #pragma unroll
            for (int ni = 0; ni < 2; ++ni)
                acc[mi][ni] = __builtin_amdgcn_mfma_f32_16x16x32_bf16(af[mi], bg[ni], acc[mi][ni], 0, 0, 0);
        __syncthreads();
        cur ^= 1;
    }
    #pragma unroll
    for (int mi = 0; mi < 4; ++mi)
        #pragma unroll
        for (int ni = 0; ni < 2; ++ni) {
            const int col = n0 + wn * 32 + ni * 16 + lr;
            const float bv = bias[col];
            const int part = col >> 8, hh = (col >> 5) & 7, dh = col & 31;
            #pragma unroll
            for (int r = 0; r < 4; ++r) {
                const int row = m0 + wm * 64 + mi * 16 + lg * 4 + r;
                const int ss = row >> 3, bb = row & 7;
                Cv[(((size_t)((part * 8 + bb) * 8 + hh)) * 1024 + ss) * 32 + dh] = f2bf(acc[mi][ni][r] + bv);
            }
        }
}

// -------------------- MFMA flash attention (double-buffered, no-max softmax) + offset scan --------------------
__global__ __launch_bounds__(512) void attn_mfma(const u16* __restrict__ qkv, u16* __restrict__ ctx,
                                                 const int* __restrict__ count, int* __restrict__ offset)
{
    const int tid = threadIdx.x;
    if (blockIdx.x == 512) {               // prefix-scan block (COUNT complete: previous dispatch)
        __shared__ int s[512];
        const int base = tid * 16;
        int c[16]; int sum = 0;
        #pragma unroll
        for (int i = 0; i < 16; ++i) { c[i] = count[base + i]; sum += c[i]; }
        s[tid] = sum; __syncthreads();
        for (int off = 1; off < 512; off <<= 1) {
            int add = (tid >= off) ? s[tid - off] : 0;
            __syncthreads();
            s[tid] += add;
            __syncthreads();
        }
        int run = (tid == 0) ? 0 : s[tid - 1];
        #pragma unroll
        for (int i = 0; i < 16; ++i) { offset[base + i] = run; run += c[i]; }
        if (tid == 511) offset[8192] = run;   // = ET_
        return;
    }
    const int qt = blockIdx.x & 7, bh = blockIdx.x >> 3;
    const int b = bh >> 3, h = bh & 7;
    const int lane = tid & 63, w = tid >> 6;
    const int c = lane & 15, g = lane >> 4;

    __shared__ __align__(16) u16 Ks[2][128][40];
    __shared__ __align__(16) u16 Vt[2][32][132];

    const size_t plane = (size_t)(b * 8 + h) * 32768;
    const int q0 = qt * 128 + w * 16;
    const bf16x8 qf = *(const bf16x8*)&qkv[plane + (size_t)(q0 + c) * 32 + g * 8];
    const u16* kbase = qkv + 2097152 + plane;

    auto stage = [&](int buf, int kt) {
        const int r = tid >> 2, c0 = (tid & 3) * 8;
        const u16* kp = kbase + (size_t)(kt * 128 + r) * 32 + c0;
        *(uint4*)&Ks[buf][r][c0] = *(const uint4*)kp;
        u16 vb[8];
        *(uint4*)vb = *(const uint4*)(kp + 2097152);
        #pragma unroll
        for (int i = 0; i < 8; ++i) Vt[buf][c0 + i][r] = vb[i];
    };

    float l = 0.f;
    f32x4 o0 = {}, o1 = {};

    stage(0, 0);
    __syncthreads();
    int cur = 0;
    for (int kt = 0; kt < 8; ++kt) {
        if (kt + 1 < 8) stage(cur ^ 1, kt + 1);
        f32x4 sc[8];
        #pragma unroll
        for (int t = 0; t < 8; ++t) {
            const bf16x8 kf = *(const bf16x8*)&Ks[cur][t * 16 + c][g * 8];
            sc[t] = __builtin_amdgcn_mfma_f32_16x16x32_bf16(kf, qf, (f32x4){0.f, 0.f, 0.f, 0.f}, 0, 0, 0);
        }
        unsigned int pb[8][2];
        float ls = 0.f;
        #pragma unroll
        for (int t = 0; t < 8; ++t) {
            const float p0 = __expf(sc[t][0] * QK_SCALE);
            const float p1 = __expf(sc[t][1] * QK_SCALE);
            const float p2 = __expf(sc[t][2] * QK_SCALE);
            const float p3 = __expf(sc[t][3] * QK_SCALE);
            ls += (p0 + p1) + (p2 + p3);
            pb[t][0] = pack_trunc(p0, p1);
            pb[t][1] = pack_trunc(p2, p3);
        }
        l += ls;
        #pragma unroll
        for (int t = 0; t < 8; ++t) {
            union { unsigned int u[2]; s16x4 v; } pu;
            pu.u[0] = pb[t][0]; pu.u[1] = pb[t][1];
            const s16x4 vf0 = *(const s16x4*)&Vt[cur][c][t * 16 + g * 4];
            const s16x4 vf1 = *(const s16x4*)&Vt[cur][16 + c][t * 16 + g * 4];
            o0 = mfma16bf(vf0, pu.v, o0);
            o1 = mfma16bf(vf1, pu.v, o1);
        }
        __syncthreads();
        cur ^= 1;
    }
    l += __shfl_xor(l, 16, 64);
    l += __shfl_xor(l, 32, 64);
    const float inv = 1.f / l;
    u16 ob[8];
    #pragma unroll
    for (int r = 0; r < 4; ++r) { ob[r] = f2bf(o0[r] * inv); ob[4 + r] = f2bf(o1[r] * inv); }
    const size_t obase = ((size_t)(q0 + c) * 8 + b) * 256 + h * 32 + g * 4;
    *(uint2*)&ctx[obase]      = *(uint2*)ob;
    *(uint2*)&ctx[obase + 16] = *(uint2*)(ob + 4);
}

// -------------------- fused out_proj GEMM + LN1 + chained XH GEMM + scores (+ scatter blocks) --------------------
// Blocks 0..255: BM=32 rows. GEMM1: X1 = LN(x + CTX@Wo^T + b) -> X1f f32 + X1s (LDS bf16).
// GEMM2 (chained): XH = X1s @ Wl^T -> XH bf16 node-major + per-head scores asrc/adst.
// Blocks >= 256: edge scatter (OFFSET ready from previous dispatch).
__global__ __launch_bounds__(512) void gemm_ln0_xh(const u16* __restrict__ A,
                                                   const u16* __restrict__ Wo,
                                                   const u16* __restrict__ Wl,
                                                   const float* __restrict__ bias,
                                                   const float* __restrict__ resid,
                                                   const float* __restrict__ gamma,
                                                   const float* __restrict__ beta,
                                                   const float* __restrict__ att_s,
                                                   const float* __restrict__ att_d,
                                                   float* __restrict__ X1f,
                                                   u16* __restrict__ XH,
                                                   float* __restrict__ asrc,
                                                   float* __restrict__ adst,
                                                   const int* __restrict__ ei,
                                                   const int* __restrict__ offset,
                                                   int* __restrict__ cursor,
                                                   int* __restrict__ sorted)
{
    const int tid = threadIdx.x;
    if (blockIdx.x >= 256) {               // scatter blocks
        const int e = (blockIdx.x - 256) * 512 + tid;   // 528*512 == ET_
        int src, dst;
        if (e < E_) { src = ei[e]; dst = ei[E_ + e]; }
        else        { src = dst = e - E_; }
        const int pos = offset[dst] + atomicAdd(&cursor[dst], 1);
        sorted[pos] = src;
        return;
    }
    __shared__ u16 As[2][32 * 32];
    __shared__ u16 Bs[2][256 * 32];
    __shared__ float2 red[32][8];
    __shared__ __align__(16) u16 X1s[32][264];   // pad 264: rows spread across banks
    const int m0 = blockIdx.x * 32;
    const int lane = tid & 63, w = tid >> 6;
    const int rw = w >> 2, cw = w & 3;
    const int lr = lane & 15, lg = lane >> 4;

    auto stageW = [&](const u16* W, int buf, int k0) {
        #pragma unroll
        for (int j = 0; j < 2; ++j) {
            const int idx = tid + j * 512;
            gload16(W + (size_t)(idx >> 2) * 256 + (idx & 3) * 8 + k0, &Bs[buf][idx * 8]);
        }
    };
    auto stageA = [&](int buf, int k0) {
        if (tid < 128)
            gload16(A + (size_t)(m0 + (tid >> 2)) * 256 + (tid & 3) * 8 + k0, &As[buf][tid * 8]);
    };

    // ---- GEMM1: CTX @ Wo^T ----
    f32x4 acc[4] = {};
    stageW(Wo, 0, 0); stageA(0, 0);
    __syncthreads();
    int cur = 0;
    for (int kt = 0; kt < 8; ++kt) {
        if (kt + 1 < 8) { stageW(Wo, cur ^ 1, (kt + 1) << 5); stageA(cur ^ 1, (kt + 1) << 5); }
        const bf16x8 af = *(const bf16x8*)&As[cur][(rw * 16 + lr) * 32 + lg * 8];
        bf16x8 bg[4];
        #pragma unroll
        for (int i = 0; i < 4; ++i)  bg[i] = *(const bf16x8*)&Bs[cur][(cw * 64 + i * 16 + lr) * 32 + lg * 8];
        #pragma unroll
        for (int ni = 0; ni < 4; ++ni)
            acc[ni] = __builtin_amdgcn_mfma_f32_16x16x32_bf16(af, bg[ni], acc[ni], 0, 0, 0);
        __syncthreads();
        cur ^= 1;
    }
    // ---- epilogue1: +bias +resid -> LN -> X1f + X1s ----
    int col[4]; float gam[4], bet[4], bv[4];
    #pragma unroll
    for (int ni = 0; ni < 4; ++ni) {
        col[ni] = cw * 64 + ni * 16 + lr;
        gam[ni] = gamma[col[ni]]; bet[ni] = beta[col[ni]]; bv[ni] = bias[col[ni]];
    }
    #pragma unroll
    for (int r = 0; r < 4; ++r) {
        const int row = rw * 16 + lg * 4 + r;
        const int grow = m0 + row;
        float s1 = 0.f, s2 = 0.f;
        #pragma unroll
        for (int ni = 0; ni < 4; ++ni) {
            float v = acc[ni][r] + bv[ni] + resid[(size_t)grow * 256 + col[ni]];
            acc[ni][r] = v;
            s1 += v; s2 += v * v;
        }
        #pragma unroll
        for (int msk = 1; msk < 16; msk <<= 1) { s1 += __shfl_xor(s1, msk, 64); s2 += __shfl_xor(s2, msk, 64); }
        if (lr == 0) red[row][cw] = (float2){s1, s2};
    }
    __syncthreads();
    #pragma unroll
    for (int r = 0; r < 4; ++r) {
        const int row = rw * 16 + lg * 4 + r;
        const int grow = m0 + row;
        const float2 t0 = red[row][0], t1 = red[row][1], t2 = red[row][2], t3 = red[row][3];
        const float mean = (t0.x + t1.x + t2.x + t3.x) * (1.f / 256.f);
        const float var  = (t0.y + t1.y + t2.y + t3.y) * (1.f / 256.f) - mean * mean;
        const float rs = rsqrtf(var + 1e-5f);
        #pragma unroll
        for (int ni = 0; ni < 4; ++ni) {
            const float o = (acc[ni][r] - mean) * rs * gam[ni] + bet[ni];
            X1f[(size_t)grow * 256 + col[ni]] = o;
            X1s[row][col[ni]] = f2bf(o);
        }
    }
    // ---- GEMM2: XH = X1s @ Wl^T ----
    f32x4 acc2[4] = {};
    stageW(Wl, 0, 0);
    __syncthreads();                      // X1s complete + Bs[0]=Wl tile (barrier drains vmcnt)
    cur = 0;
    for (int kt = 0; kt < 8; ++kt) {
        if (kt + 1 < 8) stageW(Wl, cur ^ 1, (kt + 1) << 5);
        const bf16x8 af = *(const bf16x8*)&X1s[rw * 16 + lr][kt * 32 + lg * 8];
        bf16x8 bg[4];
        #pragma unroll
        for (int i = 0; i < 4; ++i)  bg[i] = *(const bf16x8*)&Bs[cur][(cw * 64 + i * 16 + lr) * 32 + lg * 8];
        #pragma unroll
        for (int ni = 0; ni < 4; ++ni)
            acc2[ni] = __builtin_amdgcn_mfma_f32_16x16x32_bf16(af, bg[ni], acc2[ni], 0, 0, 0);
        __syncthreads();
        cur ^= 1;
    }
    // ---- epilogue2: scores + XH (node-major) ----
    float asv[4], adv[4];
    #pragma unroll
    for (int ni = 0; ni < 4; ++ni) { asv[ni] = att_s[col[ni]]; adv[ni] = att_d[col[ni]]; }
    #pragma unroll
    for (int r = 0; r < 4; ++r) {
        const int row = rw * 16 + lg * 4 + r;
        float2 sp0 = {0.f, 0.f}, sp1 = {0.f, 0.f};
        #pragma unroll
        for (int ni = 0; ni < 4; ++ni) {
            const float v = acc2[ni][r];
            if (ni < 2) { sp0.x += v * asv[ni]; sp0.y += v * adv[ni]; }
            else        { sp1.x += v * asv[ni]; sp1.y += v * adv[ni]; }
        }
        #pragma unroll
        for (int msk = 1; msk < 16; msk <<= 1) {
            sp0.x += __shfl_xor(sp0.x, msk, 64); sp0.y += __shfl_xor(sp0.y, msk, 64);
            sp1.x += __shfl_xor(sp1.x, msk, 64); sp1.y += __shfl_xor(sp1.y, msk, 64);
        }
        if (lr == 0) { red[row][cw * 2] = sp0; red[row][cw * 2 + 1] = sp1; }
    }
    __syncthreads();
    #pragma unroll
    for (int r = 0; r < 4; ++r) {
        const int grow = m0 + rw * 16 + lg * 4 + r;
        const int node = (grow & 7) * 1024 + (grow >> 3);
        #pragma unroll
        for (int ni = 0; ni < 4; ++ni)
            XH[(size_t)node * 256 + col[ni]] = f2bf(acc2[ni][r]);
    }
    for (int idx = tid; idx < 32 * 8; idx += 512) {
        const int row = idx >> 3, h = idx & 7;
        const int grow = m0 + row;
        const int node = (grow & 7) * 1024 + (grow >> 3);
        asrc[(size_t)node * 8 + h] = red[row][h].x;
        adst[(size_t)node * 8 + h] = red[row][h].y;
    }
}

// -------------------- fused GEMM + LN (final): out = LN(X2 + Hb@W2^T + b) --------------------
__global__ __launch_bounds__(512) void gemm_ln2(const u16* __restrict__ A, int lda,
                                                const u16* __restrict__ W, int ldw, int Ksz,
                                                const float* __restrict__ bias,
                                                const float* __restrict__ resid,
                                                const float* __restrict__ gamma,
                                                const float* __restrict__ beta,
                                                float* __restrict__ outf)
{
    constexpr int BM = 32;
    const int tid = threadIdx.x;
    __shared__ u16 As[2][BM * 32];
    __shared__ u16 Bs[2][256 * 32];
    __shared__ float2 red[BM][8];
    const int m0 = blockIdx.x * BM;
    const int lane = tid & 63, w = tid >> 6;
    const int rw = w >> 2, cw = w & 3;
    const int lr = lane & 15, lg = lane >> 4;

    f32x4 acc[4] = {};

    auto stage = [&](int buf, int k0) {
        #pragma unroll
        for (int j = 0; j < 2; ++j) {
            const int idx = tid + j * 512;
            gload16(W + (size_t)(idx >> 2) * ldw + (idx & 3) * 8 + k0, &Bs[buf][idx * 8]);
        }
        if (tid < BM * 4)
            gload16(A + (size_t)(m0 + (tid >> 2)) * lda + (tid & 3) * 8 + k0, &As[buf][tid * 8]);
    };
    stage(0, 0);
    __syncthreads();
    const int nt = Ksz >> 5;
    int cur = 0;
    for (int kt = 0; kt < nt; ++kt) {
        if (kt + 1 < nt) stage(cur ^ 1, (kt + 1) << 5);
        bf16x8 af = *(const bf16x8*)&As[cur][(rw * 16 + lr) * 32 + lg * 8];
        bf16x8 bg[4];
        #pragma unroll
        for (int i = 0; i < 4; ++i)  bg[i] = *(const bf16x8*)&Bs[cur][(cw * 64 + i * 16 + lr) * 32 + lg * 8];
        #pragma unroll
        for (int ni = 0; ni < 4; ++ni)
            acc[ni] = __builtin_amdgcn_mfma_f32_16x16x32_bf16(af, bg[ni], acc[ni], 0, 0, 0);
        __syncthreads();
        cur ^= 1;
    }
    int col[4]; float gam[4], bet[4], bv[4];
    #pragma unroll
    for (int ni = 0; ni < 4; ++ni) {
        col[ni] = cw * 64 + ni * 16 + lr;
        gam[ni] = gamma[col[ni]]; bet[ni] = beta[col[ni]]; bv[ni] = bias[col[ni]];
    }
    #pragma unroll
    for (int r = 0; r < 4; ++r) {
        const int row = rw * 16 + lg * 4 + r;
        const int grow = m0 + row;
        float s1 = 0.f, s2 = 0.f;
        #pragma unroll
        for (int ni = 0; ni < 4; ++ni) {
            float v = acc[ni][r] + bv[ni] + resid[(size_t)grow * 256 + col[ni]];
            acc[ni][r] = v;
            s1 += v; s2 += v * v;
        }
        #pragma unroll
        for (int msk = 1; msk < 16; msk <<= 1) { s1 += __shfl_xor(s1, msk, 64); s2 += __shfl_xor(s2, msk, 64); }
        if (lr == 0) red[row][cw] = (float2){s1, s2};
    }
    __syncthreads();
    #pragma unroll
    for (int r = 0; r < 4; ++r) {
        const int row = rw * 16 + lg * 4 + r;
        const int grow = m0 + row;
        const float2 t0 = red[row][0], t1 = red[row][1], t2 = red[row][2], t3 = red[row][3];
        const float mean = (t0.x + t1.x + t2.x + t3.x) * (1.f / 256.f);
        const float var  = (t0.y + t1.y + t2.y + t3.y) * (1.f / 256.f) - mean * mean;
        const float rs = rsqrtf(var + 1e-5f);
        #pragma unroll
        for (int ni = 0; ni < 4; ++ni)
            outf[(size_t)grow * 256 + col[ni]] = (acc[ni][r] - mean) * rs * gam[ni] + bet[ni];
    }
}

// -------------------- GAT gather + residual + LN2: 2 waves/dst, dual-edge lane split, no max --------------------
__global__ __launch_bounds__(256) void gat_gather_ln(const int* __restrict__ sorted, const int* __restrict__ offset,
                                                     const float* __restrict__ asrc, const float* __restrict__ adst,
                                                     const u16* __restrict__ xh,
                                                     const float* __restrict__ X1f, const float* __restrict__ gb,
                                                     const float* __restrict__ g2, const float* __restrict__ be2,
                                                     const float* __restrict__ cond,
                                                     float* __restrict__ X2f, u16* __restrict__ X2pad)
{
    const int wid = threadIdx.x >> 6, lane = threadIdx.x & 63;
    const int pair = wid >> 1, half = wid & 1;
    const int dst = blockIdx.x * 2 + pair;
    const int sub = lane >> 5, l32 = lane & 31;
    const int h = l32 >> 2;                     // head of dims 8*l32..+7
    const float ad = adst[dst * 8 + h];
    const int beg = offset[dst], end = offset[dst + 1];
    const int mid = beg + ((end - beg + 1) >> 1);
    const int b0 = half ? mid : beg;
    const int b1 = half ? end : mid;

    __shared__ float szs[2][8];
    __shared__ __align__(16) float sa[2][32][8];

    float z = 0.f;
    float a[8] = {};
    #pragma unroll 2
    for (int i = b0 + sub; i < b1; i += 2) {
        const int src = sorted[i];
        float e = asrc[src * 8 + h] + ad;
        e = fmaxf(e, 0.2f * e);
        const float p = __expf(e);
        z += p;
        const uint4 xv = *(const uint4*)&xh[(size_t)src * 256 + l32 * 8];
        a[0] += p * __uint_as_float(xv.x << 16);
        a[1] += p * __uint_as_float(xv.x & 0xffff0000u);
        a[2] += p * __uint_as_float(xv.y << 16);
        a[3] += p * __uint_as_float(xv.y & 0xffff0000u);
        a[4] += p * __uint_as_float(xv.z << 16);
        a[5] += p * __uint_as_float(xv.z & 0xffff0000u);
        a[6] += p * __uint_as_float(xv.w << 16);
        a[7] += p * __uint_as_float(xv.w & 0xffff0000u);
    }
    // combine the two 32-lane sub-halves
    z += __shfl_xor(z, 32, 64);
    #pragma unroll
    for (int j = 0; j < 8; ++j) a[j] += __shfl_xor(a[j], 32, 64);
    // cross-wave merge (half 1 -> LDS)
    if (half && sub == 0) {
        if ((l32 & 3) == 0) szs[pair][h] = z;
        *(f32x4*)&sa[pair][l32][0] = (f32x4){a[0], a[1], a[2], a[3]};
        *(f32x4*)&sa[pair][l32][4] = (f32x4){a[4], a[5], a[6], a[7]};
    }
    __syncthreads();
    if (half) return;
    const float zt = z + szs[pair][h];
    const float inv = 1.f / zt;
    const int row = (dst & 1023) * 8 + (dst >> 10);    // dst = b*1024 + s -> row = s*8 + b
    float v[8];
    {
        const f32x4 x0 = *(const f32x4*)&X1f[(size_t)row * 256 + l32 * 8];
        const f32x4 x1 = *(const f32x4*)&X1f[(size_t)row * 256 + l32 * 8 + 4];
        const f32x4 gb0 = *(const f32x4*)&gb[l32 * 8];
        const f32x4 gb1 = *(const f32x4*)&gb[l32 * 8 + 4];
        const f32x4 m0 = *(const f32x4*)&sa[pair][l32][0];
        const f32x4 m1 = *(const f32x4*)&sa[pair][l32][4];
        #pragma unroll
        for (int j = 0; j < 4; ++j) {
            v[j]     = x0[j] + (a[j] + m0[j]) * inv + gb0[j];
            v[4 + j] = x1[j] + (a[4 + j] + m1[j]) * inv + gb1[j];
        }
    }
    float s1 = 0.f, s2 = 0.f;
    #pragma unroll
    for (int j = 0; j < 8; ++j) { s1 += v[j]; s2 += v[j] * v[j]; }
    #pragma unroll
    for (int msk = 1; msk < 32; msk <<= 1) { s1 += __shfl_xor(s1, msk, 64); s2 += __shfl_xor(s2, msk, 64); }
    const float mean = s1 * (1.f / 256.f);
    const float var = s2 * (1.f / 256.f) - mean * mean;
    const float rs = rsqrtf(var + 1e-5f);
    if (sub == 0) {
        const f32x4 gg0 = *(const f32x4*)&g2[l32 * 8];
        const f32x4 gg1 = *(const f32x4*)&g2[l32 * 8 + 4];
        const f32x4 be0 = *(const f32x4*)&be2[l32 * 8];
        const f32x4 be1 = *(const f32x4*)&be2[l32 * 8 + 4];
        f32x4 o0, o1;
        u16 ob[8];
        #pragma unroll
        for (int j = 0; j < 4; ++j) {
            o0[j] = (v[j] - mean) * rs * gg0[j] + be0[j];
            o1[j] = (v[4 + j] - mean) * rs * gg1[j] + be1[j];
            ob[j] = f2bf(o0[j]); ob[4 + j] = f2bf(o1[j]);
        }
        *(f32x4*)&X2f[(size_t)row * 256 + l32 * 8]     = o0;
        *(f32x4*)&X2f[(size_t)row * 256 + l32 * 8 + 4] = o1;
        *(uint4*)&X2pad[(size_t)row * 288 + l32 * 8] = *(uint4*)ob;
        if (l32 < 8) {
            u16 zz[4] = {0, 0, 0, 0};
            if (l32 == 0) zz[0] = f2bf(cond[row]);
            *(uint2*)&X2pad[(size_t)row * 288 + 256 + l32 * 4] = *(uint2*)zz;
        }
    }
}

// -------------------- FFN w1 GEMM (128x128 tile) --------------------
__global__ __launch_bounds__(256) void gemm_w1(const u16* __restrict__ A,
                                               const u16* __restrict__ W,
                                               const float* __restrict__ bias,
                                               u16* __restrict__ Cv)
{
    __shared__ u16 As[2][128 * 32];
    __shared__ u16 Bs[2][128 * 32];
    const int tid = threadIdx.x;
    const int m0 = blockIdx.y * 128, n0 = blockIdx.x * 128;
    const int lane = tid & 63, w = tid >> 6;
    const int wm = w >> 1, wn = w & 1;
    const int lr = lane & 15, lg = lane >> 4;

    f32x4 acc[4][4] = {};

    const u16* Ag = A + (size_t)(m0 + (tid >> 2)) * 288 + (tid & 3) * 8;
    const u16* Wg = W + (size_t)(n0 + (tid >> 2)) * 288 + (tid & 3) * 8;

    auto stage = [&](int buf, int k0) {
        gload16(Ag + k0,                    &As[buf][tid * 8]);
        gload16(Ag + (size_t)64 * 288 + k0, &As[buf][64 * 32 + tid * 8]);
        gload16(Wg + k0,                    &Bs[buf][tid * 8]);
        gload16(Wg + (size_t)64 * 288 + k0, &Bs[buf][64 * 32 + tid * 8]);
    };
    stage(0, 0);
    __syncthreads();
    int cur = 0;
    for (int kt = 0; kt < 9; ++kt) {
        if (kt + 1 < 9) stage(cur ^ 1, (kt + 1) << 5);
        bf16x8 af[4], bg[4];
        #pragma unroll
        for (int i = 0; i < 4; ++i) {
            af[i] = *(const bf16x8*)&As[cur][(wm * 64 + i * 16 + lr) * 32 + lg * 8];
            bg[i] = *(const bf16x8*)&Bs[cur][(wn * 64 + i * 16 + lr) * 32 + lg * 8];
        }
        #pragma unroll
        for (int mi = 0; mi < 4; ++mi)
            #pragma unroll
            for (int ni = 0; ni < 4; ++ni)
                acc[mi][ni] = __builtin_amdgcn_mfma_f32_16x16x32_bf16(af[mi], bg[ni], acc[mi][ni], 0, 0, 0);
        __syncthreads();
        cur ^= 1;
    }
    #pragma unroll
    for (int mi = 0; mi < 4; ++mi)
        #pragma unroll
        for (int ni = 0; ni < 4; ++ni) {
            const int col = n0 + wn * 64 + ni * 16 + lr;
            const float bv = bias[col];
            #pragma unroll
            for (int r = 0; r < 4; ++r) {
                const int row = m0 + wm * 64 + mi * 16 + lg * 4 + r;
                Cv[(size_t)row * 1024 + col] = f2bf(fmaxf(acc[mi][ni][r] + bv, 0.f));
            }
        }
}

extern "C" void kernel_launch(void* const* d_in, const int* in_sizes, int n_in,
                              void* d_out, int out_size, void* d_ws, size_t ws_size,
                              hipStream_t stream)
{
    const float* x          = (const float*)d_in[0];
    const float* condition  = (const float*)d_in[1];
    const float* in_proj_w  = (const float*)d_in[2];
    const float* in_proj_b  = (const float*)d_in[3];
    const float* out_proj_w = (const float*)d_in[4];
    const float* out_proj_b = (const float*)d_in[5];
    const float* g1         = (const float*)d_in[6];
    const float* be1        = (const float*)d_in[7];
    const float* g2         = (const float*)d_in[8];
    const float* be2        = (const float*)d_in[9];
    const float* g3         = (const float*)d_in[10];
    const float* be3        = (const float*)d_in[11];
    const float* lin_w      = (const float*)d_in[12];
    const float* att_src    = (const float*)d_in[13];
    const float* att_dst    = (const float*)d_in[14];
    const float* gat_bias   = (const float*)d_in[15];
    const float* w1         = (const float*)d_in[16];
    const float* bf1        = (const float*)d_in[17];
    const float* w2         = (const float*)d_in[18];
    const float* bf2        = (const float*)d_in[19];
    const int*   edge_index = (const int*)d_in[20];
    float* out = (float*)d_out;

    char* ws = (char*)d_ws;
    u16*   QKV    = (u16*)(ws + 0);              // 12.6MB [QKV gemm, attn]
    u16*   Hb     = (u16*)(ws + 0);              // 16MB   [w1 gemm, w2 gemm] (QKV dead)
    u16*   CTX    = (u16*)(ws + 16777216);       // 4MB    [attn, ln1-gemm]
    u16*   XH     = (u16*)(ws + 25165824);       // 4MB    [ln1-gemm, gather]
    float* X1f    = (float*)(ws + 29360128);     // 8MB    [ln1-gemm, gather]
    float* X2f    = (float*)(ws + 37748736);     // 8MB    [gather, w2-gemm]
    u16*   X2pad  = (u16*)(ws + 46137344);       // 4.72MB [gather, w1 gemm]
    u16*   Xbf    = (u16*)(ws + 50855936);       // 4MB    [convert, QKV gemm]
    float* ASRC   = (float*)(ws + 55050240);     // 256KB
    float* ADST   = (float*)(ws + 55312384);     // 256KB
    u16*   W_inp  = (u16*)(ws + 55574528);       // 393,216
    u16*   W_out  = (u16*)(ws + 55967744);       // 131,072
    u16*   W_lin  = (u16*)(ws + 56098816);       // 131,072
    u16*   W_w1   = (u16*)(ws + 56229888);       // 589,824 (1024 x 288)
    u16*   W_w2   = (u16*)(ws + 56819712);       // 524,288
    int*   COUNT  = (int*)(ws + 57344000);       // 32,768
    int*   OFFSET = (int*)(ws + 57376768);       // 36,864 (8193 used)
    int*   CURSOR = (int*)(ws + 57413632);       // 32,768
    int*   SORTED = (int*)(ws + 57446400);       // 1,081,344 -> ends 58,527,744

    // 1. conversions (x vectorized) + zero sort counters
    convert_all<<<5568, 256, 0, stream>>>(x, in_proj_w, out_proj_w, lin_w, w1, w2,
                                          Xbf, W_inp, W_out, W_lin, W_w1, W_w2, COUNT, CURSOR);
    // 2. QKV GEMM (768 blocks) + edge histogram (1056 blocks)
    gemm_qkv_hist<<<1824, 256, 0, stream>>>(Xbf, W_inp, in_proj_b, QKV, edge_index, COUNT);
    // 3. flash attention (512 blocks, double-buffered, no-max softmax) + offset scan (1 block)
    attn_mfma<<<513, 512, 0, stream>>>(QKV, CTX, COUNT, OFFSET);
    // 4. X1 = LN(x + CTX@Wo^T + b) -> X1f; chained XH = X1 @ Wl^T -> XH + scores (256 blocks)
    //    + edge scatter (528 blocks)
    gemm_ln0_xh<<<784, 512, 0, stream>>>(CTX, W_out, W_lin, out_proj_b, x, g1, be1,
                                         att_src, att_dst, X1f, XH, ASRC, ADST,
                                         edge_index, OFFSET, CURSOR, SORTED);
    // 5. gather + residual + LN2 -> X2f f32 + X2pad bf16 (K=288 w/ cond col)
    gat_gather_ln<<<4096, 256, 0, stream>>>(SORTED, OFFSET, ASRC, ADST, XH,
                                            X1f, gat_bias, g2, be2, condition, X2f, X2pad);
    // 6. H = relu(X2pad @ W_w1^T + bf1)
    gemm_w1<<<dim3(8, 64), 256, 0, stream>>>(X2pad, W_w1, bf1, Hb);
    // 7. out = LN(X2 + Hb@W_w2^T + bf2)
    gemm_ln2<<<256, 512, 0, stream>>>(Hb, 1024, W_w2, 1024, 1024, bf2, X2f, g3, be3, out);
}

// Round 18
// 133.410 us; speedup vs baseline: 1.0597x; 1.0028x over previous
//
#include <hip/hip_runtime.h>
#include <hip/hip_bf16.h>

// Problem constants
#define S_ 1024
#define B_ 8
#define D_ 256
#define H_ 8
#define DH_ 32
#define N_ 8192           // S*B nodes
#define E_ 262144
#define ET_ 270336        // E + N (self loops)

typedef unsigned short u16;
typedef float f32x4 __attribute__((ext_vector_type(4)));
typedef __bf16 bf16x8 __attribute__((ext_vector_type(8)));
typedef short s16x4 __attribute__((ext_vector_type(4)));

#define QK_SCALE 0.17677669529663687f  // 1/sqrt(32)

// f32 -> bf16 (RNE)
__device__ inline u16 f2bf(float v) {
    unsigned int u = __float_as_uint(v);
    u = (u + 0x7fffu + ((u >> 16) & 1u)) >> 16;
    return (u16)u;
}
__device__ inline float bf2f(u16 u) { return __uint_as_float(((unsigned int)u) << 16); }

// pack two f32 -> two bf16 (truncation) in one v_perm
__device__ inline unsigned int pack_trunc(float lo, float hi) {
    return __builtin_amdgcn_perm(__float_as_uint(hi), __float_as_uint(lo), 0x07060302u);
}

// async global->LDS 16B
__device__ inline void gload16(const u16* g, u16* l) {
    __builtin_amdgcn_global_load_lds((const __attribute__((address_space(1))) unsigned int*)g,
                                     (__attribute__((address_space(3))) unsigned int*)l, 16, 0, 0);
}

// K=16 bf16 MFMA
__device__ inline f32x4 mfma16bf(s16x4 a, s16x4 b, f32x4 c) {
#if __has_builtin(__builtin_amdgcn_mfma_f32_16x16x16bf16_1k)
    return __builtin_amdgcn_mfma_f32_16x16x16bf16_1k(a, b, c, 0, 0, 0);
#else
    asm volatile("v_mfma_f32_16x16x16_bf16 %0, %1, %2, %0" : "+v"(c) : "v"(a), "v"(b));
    return c;
#endif
}

// -------------------- fused conversions (x vectorized 4x) + zero-init of sort counters --------------------
__global__ __launch_bounds__(256) void convert_all(const float* __restrict__ x,  const float* __restrict__ wi,
                                                   const float* __restrict__ wo, const float* __restrict__ wl,
                                                   const float* __restrict__ w1, const float* __restrict__ w2,
                                                   u16* __restrict__ Xbf, u16* __restrict__ Wi, u16* __restrict__ Wo,
                                                   u16* __restrict__ Wl, u16* __restrict__ W1, u16* __restrict__ W2,
                                                   int* __restrict__ count, int* __restrict__ cursor)
{
    const int idx = blockIdx.x * 256 + threadIdx.x;
    const int C0 = 524288;             // x as float4 units: 8192*256/4
    const int C1 = C0 + 196608;        // in_proj 768*256
    const int C2 = C1 + 65536;         // out_proj
    const int C3 = C2 + 65536;         // lin
    const int C4 = C3 + 294912;        // w1 padded 1024*288 (kin 257)
    const int C5 = C4 + 262144;        // w2 256*1024
    const int C6 = C5 + 16384;         // zero COUNT(8192) + CURSOR(8192)
    if (idx < C0) {
        const float4 v = *(const float4*)&x[(size_t)idx * 4];
        u16 o[4] = {f2bf(v.x), f2bf(v.y), f2bf(v.z), f2bf(v.w)};
        *(uint2*)&Xbf[(size_t)idx * 4] = *(uint2*)o;
    }
    else if (idx < C1) { int i = idx - C0; Wi[i] = f2bf(wi[i]); }
    else if (idx < C2) { int i = idx - C1; Wo[i] = f2bf(wo[i]); }
    else if (idx < C3) { int i = idx - C2; Wl[i] = f2bf(wl[i]); }
    else if (idx < C4) { int i = idx - C3; int r = i / 288, k = i - r * 288;
                         W1[i] = (k < 257) ? f2bf(w1[r * 257 + k]) : (u16)0; }
    else if (idx < C5) { int i = idx - C4; W2[i] = f2bf(w2[i]); }
    else if (idx < C6) { int i = idx - C5; if (i < 8192) count[i] = 0; else cursor[i - 8192] = 0; }
}

// -------------------- QKV GEMM (BN=64, QKV layout out) + edge histogram in extra blocks --------------------
__global__ __launch_bounds__(256) void gemm_qkv_hist(const u16* __restrict__ A,
                                                     const u16* __restrict__ W,
                                                     const float* __restrict__ bias,
                                                     u16* __restrict__ Cv,
                                                     const int* __restrict__ ei, int* __restrict__ count)
{
    const int tid = threadIdx.x;
    if (blockIdx.x >= 768) {               // histogram blocks (COUNT zeroed by convert_all)
        const int e = (blockIdx.x - 768) * 256 + tid;   // 1056*256 == ET_
        const int dst = (e < E_) ? ei[E_ + e] : e - E_;
        atomicAdd(&count[dst], 1);
        return;
    }
    __shared__ u16 As[2][128 * 32];
    __shared__ u16 Bs[2][64 * 32];
    const int m0 = (blockIdx.x / 12) * 128, n0 = (blockIdx.x % 12) * 64;
    const int lane = tid & 63, w = tid >> 6;
    const int wm = w >> 1, wn = w & 1;
    const int lr = lane & 15, lg = lane >> 4;

    f32x4 acc[4][2] = {};

    const u16* Ag = A + (size_t)(m0 + (tid >> 2)) * 256 + (tid & 3) * 8;
    const u16* Wg = W + (size_t)(n0 + (tid >> 2)) * 256 + (tid & 3) * 8;

    auto stage = [&](int buf, int k0) {
        gload16(Ag + k0,                    &As[buf][tid * 8]);
        gload16(Ag + (size_t)64 * 256 + k0, &As[buf][64 * 32 + tid * 8]);
        gload16(Wg + k0,                    &Bs[buf][tid * 8]);
    };
    stage(0, 0);
    __syncthreads();
    int cur = 0;
    for (int kt = 0; kt < 8; ++kt) {
        if (kt + 1 < 8) stage(cur ^ 1, (kt + 1) << 5);
        bf16x8 af[4], bg[2];
        #pragma unroll
        for (int i = 0; i < 4; ++i) af[i] = *(const bf16x8*)&As[cur][(wm * 64 + i * 16 + lr) * 32 + lg * 8];
        #pragma unroll
        for (int i = 0; i < 2; ++i) bg[i] = *(const bf16x8*)&Bs[cur][(wn * 32 + i * 16 + lr) * 32 + lg * 8];
        #pragma unroll
        for (int mi = 0; mi < 4; ++mi)
            #pragma unroll
            for (int ni = 0; ni < 2; ++ni)
                acc[mi][ni] = __builtin_amdgcn_mfma_f32_16x16x32_bf16(af[mi], bg[ni], acc[mi][ni], 0, 0, 0);
        __syncthreads();
        cur ^= 1;
    }
    #pragma unroll
    for (int mi = 0; mi < 4; ++mi)
        #pragma unroll
        for (int ni = 0; ni < 2; ++ni) {
            const int col = n0 + wn * 32 + ni * 16 + lr;
            const float bv = bias[col];
            const int part = col >> 8, hh = (col >> 5) & 7, dh = col & 31;
            #pragma unroll
            for (int r = 0; r < 4; ++r) {
                const int row = m0 + wm * 64 + mi * 16 + lg * 4 + r;
                const int ss = row >> 3, bb = row & 7;
                Cv[(((size_t)((part * 8 + bb) * 8 + hh)) * 1024 + ss) * 32 + dh] = f2bf(acc[mi][ni][r] + bv);
            }
        }
}

// -------------------- MFMA flash attention (double-buffered, no-max softmax) + offset scan --------------------
__global__ __launch_bounds__(512) void attn_mfma(const u16* __restrict__ qkv, u16* __restrict__ ctx,
                                                 const int* __restrict__ count, int* __restrict__ offset)
{
    const int tid = threadIdx.x;
    if (blockIdx.x == 512) {               // prefix-scan block (COUNT complete: previous dispatch)
        __shared__ int s[512];
        const int base = tid * 16;
        int c[16]; int sum = 0;
        #pragma unroll
        for (int i = 0; i < 16; ++i) { c[i] = count[base + i]; sum += c[i]; }
        s[tid] = sum; __syncthreads();
        for (int off = 1; off < 512; off <<= 1) {
            int add = (tid >= off) ? s[tid - off] : 0;
            __syncthreads();
            s[tid] += add;
            __syncthreads();
        }
        int run = (tid == 0) ? 0 : s[tid - 1];
        #pragma unroll
        for (int i = 0; i < 16; ++i) { offset[base + i] = run; run += c[i]; }
        if (tid == 511) offset[8192] = run;   // = ET_
        return;
    }
    const int qt = blockIdx.x & 7, bh = blockIdx.x >> 3;
    const int b = bh >> 3, h = bh & 7;
    const int lane = tid & 63, w = tid >> 6;
    const int c = lane & 15, g = lane >> 4;

    __shared__ __align__(16) u16 Ks[2][128][40];
    __shared__ __align__(16) u16 Vt[2][32][132];

    const size_t plane = (size_t)(b * 8 + h) * 32768;
    const int q0 = qt * 128 + w * 16;
    const bf16x8 qf = *(const bf16x8*)&qkv[plane + (size_t)(q0 + c) * 32 + g * 8];
    const u16* kbase = qkv + 2097152 + plane;

    auto stage = [&](int buf, int kt) {
        const int r = tid >> 2, c0 = (tid & 3) * 8;
        const u16* kp = kbase + (size_t)(kt * 128 + r) * 32 + c0;
        *(uint4*)&Ks[buf][r][c0] = *(const uint4*)kp;
        u16 vb[8];
        *(uint4*)vb = *(const uint4*)(kp + 2097152);
        #pragma unroll
        for (int i = 0; i < 8; ++i) Vt[buf][c0 + i][r] = vb[i];
    };

    float l = 0.f;
    f32x4 o0 = {}, o1 = {};

    stage(0, 0);
    __syncthreads();
    int cur = 0;
    for (int kt = 0; kt < 8; ++kt) {
        if (kt + 1 < 8) stage(cur ^ 1, kt + 1);
        f32x4 sc[8];
        #pragma unroll
        for (int t = 0; t < 8; ++t) {
            const bf16x8 kf = *(const bf16x8*)&Ks[cur][t * 16 + c][g * 8];
            sc[t] = __builtin_amdgcn_mfma_f32_16x16x32_bf16(kf, qf, (f32x4){0.f, 0.f, 0.f, 0.f}, 0, 0, 0);
        }
        unsigned int pb[8][2];
        float ls = 0.f;
        #pragma unroll
        for (int t = 0; t < 8; ++t) {
            const float p0 = __expf(sc[t][0] * QK_SCALE);
            const float p1 = __expf(sc[t][1] * QK_SCALE);
            const float p2 = __expf(sc[t][2] * QK_SCALE);
            const float p3 = __expf(sc[t][3] * QK_SCALE);
            ls += (p0 + p1) + (p2 + p3);
            pb[t][0] = pack_trunc(p0, p1);
            pb[t][1] = pack_trunc(p2, p3);
        }
        l += ls;
        #pragma unroll
        for (int t = 0; t < 8; ++t) {
            union { unsigned int u[2]; s16x4 v; } pu;
            pu.u[0] = pb[t][0]; pu.u[1] = pb[t][1];
            const s16x4 vf0 = *(const s16x4*)&Vt[cur][c][t * 16 + g * 4];
            const s16x4 vf1 = *(const s16x4*)&Vt[cur][16 + c][t * 16 + g * 4];
            o0 = mfma16bf(vf0, pu.v, o0);
            o1 = mfma16bf(vf1, pu.v, o1);
        }
        __syncthreads();
        cur ^= 1;
    }
    l += __shfl_xor(l, 16, 64);
    l += __shfl_xor(l, 32, 64);
    const float inv = 1.f / l;
    u16 ob[8];
    #pragma unroll
    for (int r = 0; r < 4; ++r) { ob[r] = f2bf(o0[r] * inv); ob[4 + r] = f2bf(o1[r] * inv); }
    const size_t obase = ((size_t)(q0 + c) * 8 + b) * 256 + h * 32 + g * 4;
    *(uint2*)&ctx[obase]      = *(uint2*)ob;
    *(uint2*)&ctx[obase + 16] = *(uint2*)(ob + 4);
}

// -------------------- fused out_proj GEMM + LN1 + chained XH GEMM + scores (+ scatter blocks) --------------------
__global__ __launch_bounds__(512) void gemm_ln0_xh(const u16* __restrict__ A,
                                                   const u16* __restrict__ Wo,
                                                   const u16* __restrict__ Wl,
                                                   const float* __restrict__ bias,
                                                   const float* __restrict__ resid,
                                                   const float* __restrict__ gamma,
                                                   const float* __restrict__ beta,
                                                   const float* __restrict__ att_s,
                                                   const float* __restrict__ att_d,
                                                   float* __restrict__ X1f,
                                                   u16* __restrict__ XH,
                                                   float* __restrict__ asrc,
                                                   float* __restrict__ adst,
                                                   const int* __restrict__ ei,
                                                   const int* __restrict__ offset,
                                                   int* __restrict__ cursor,
                                                   int* __restrict__ sorted)
{
    const int tid = threadIdx.x;
    if (blockIdx.x >= 256) {               // scatter blocks
        const int e = (blockIdx.x - 256) * 512 + tid;   // 528*512 == ET_
        int src, dst;
        if (e < E_) { src = ei[e]; dst = ei[E_ + e]; }
        else        { src = dst = e - E_; }
        const int pos = offset[dst] + atomicAdd(&cursor[dst], 1);
        sorted[pos] = src;
        return;
    }
    __shared__ u16 As[2][32 * 32];
    __shared__ u16 Bs[2][256 * 32];
    __shared__ float2 red[32][8];
    __shared__ __align__(16) u16 X1s[32][264];
    const int m0 = blockIdx.x * 32;
    const int lane = tid & 63, w = tid >> 6;
    const int rw = w >> 2, cw = w & 3;
    const int lr = lane & 15, lg = lane >> 4;

    auto stageW = [&](const u16* W, int buf, int k0) {
        #pragma unroll
        for (int j = 0; j < 2; ++j) {
            const int idx = tid + j * 512;
            gload16(W + (size_t)(idx >> 2) * 256 + (idx & 3) * 8 + k0, &Bs[buf][idx * 8]);
        }
    };
    auto stageA = [&](int buf, int k0) {
        if (tid < 128)
            gload16(A + (size_t)(m0 + (tid >> 2)) * 256 + (tid & 3) * 8 + k0, &As[buf][tid * 8]);
    };

    // ---- GEMM1: CTX @ Wo^T ----
    f32x4 acc[4] = {};
    stageW(Wo, 0, 0); stageA(0, 0);
    __syncthreads();
    int cur = 0;
    for (int kt = 0; kt < 8; ++kt) {
        if (kt + 1 < 8) { stageW(Wo, cur ^ 1, (kt + 1) << 5); stageA(cur ^ 1, (kt + 1) << 5); }
        const bf16x8 af = *(const bf16x8*)&As[cur][(rw * 16 + lr) * 32 + lg * 8];
        bf16x8 bg[4];
        #pragma unroll
        for (int i = 0; i < 4; ++i)  bg[i] = *(const bf16x8*)&Bs[cur][(cw * 64 + i * 16 + lr) * 32 + lg * 8];
        #pragma unroll
        for (int ni = 0; ni < 4; ++ni)
            acc[ni] = __builtin_amdgcn_mfma_f32_16x16x32_bf16(af, bg[ni], acc[ni], 0, 0, 0);
        __syncthreads();
        cur ^= 1;
    }
    // ---- epilogue1 ----
    int col[4]; float gam[4], bet[4], bv[4];
    #pragma unroll
    for (int ni = 0; ni < 4; ++ni) {
        col[ni] = cw * 64 + ni * 16 + lr;
        gam[ni] = gamma[col[ni]]; bet[ni] = beta[col[ni]]; bv[ni] = bias[col[ni]];
    }
    #pragma unroll
    for (int r = 0; r < 4; ++r) {
        const int row = rw * 16 + lg * 4 + r;
        const int grow = m0 + row;
        float s1 = 0.f, s2 = 0.f;
        #pragma unroll
        for (int ni = 0; ni < 4; ++ni) {
            float v = acc[ni][r] + bv[ni] + resid[(size_t)grow * 256 + col[ni]];
            acc[ni][r] = v;
            s1 += v; s2 += v * v;
        }
        #pragma unroll
        for (int msk = 1; msk < 16; msk <<= 1) { s1 += __shfl_xor(s1, msk, 64); s2 += __shfl_xor(s2, msk, 64); }
        if (lr == 0) red[row][cw] = (float2){s1, s2};
    }
    __syncthreads();
    #pragma unroll
    for (int r = 0; r < 4; ++r) {
        const int row = rw * 16 + lg * 4 + r;
        const int grow = m0 + row;
        const float2 t0 = red[row][0], t1 = red[row][1], t2 = red[row][2], t3 = red[row][3];
        const float mean = (t0.x + t1.x + t2.x + t3.x) * (1.f / 256.f);
        const float var  = (t0.y + t1.y + t2.y + t3.y) * (1.f / 256.f) - mean * mean;
        const float rs = rsqrtf(var + 1e-5f);
        #pragma unroll
        for (int ni = 0; ni < 4; ++ni) {
            const float o = (acc[ni][r] - mean) * rs * gam[ni] + bet[ni];
            X1f[(size_t)grow * 256 + col[ni]] = o;
            X1s[row][col[ni]] = f2bf(o);
        }
    }
    // ---- GEMM2: XH = X1s @ Wl^T ----
    f32x4 acc2[4] = {};
    stageW(Wl, 0, 0);
    __syncthreads();
    cur = 0;
    for (int kt = 0; kt < 8; ++kt) {
        if (kt + 1 < 8) stageW(Wl, cur ^ 1, (kt + 1) << 5);
        const bf16x8 af = *(const bf16x8*)&X1s[rw * 16 + lr][kt * 32 + lg * 8];
        bf16x8 bg[4];
        #pragma unroll
        for (int i = 0; i < 4; ++i)  bg[i] = *(const bf16x8*)&Bs[cur][(cw * 64 + i * 16 + lr) * 32 + lg * 8];
        #pragma unroll
        for (int ni = 0; ni < 4; ++ni)
            acc2[ni] = __builtin_amdgcn_mfma_f32_16x16x32_bf16(af, bg[ni], acc2[ni], 0, 0, 0);
        __syncthreads();
        cur ^= 1;
    }
    // ---- epilogue2 ----
    float asv[4], adv[4];
    #pragma unroll
    for (int ni = 0; ni < 4; ++ni) { asv[ni] = att_s[col[ni]]; adv[ni] = att_d[col[ni]]; }
    #pragma unroll
    for (int r = 0; r < 4; ++r) {
        const int row = rw * 16 + lg * 4 + r;
        float2 sp0 = {0.f, 0.f}, sp1 = {0.f, 0.f};
        #pragma unroll
        for (int ni = 0; ni < 4; ++ni) {
            const float v = acc2[ni][r];
            if (ni < 2) { sp0.x += v * asv[ni]; sp0.y += v * adv[ni]; }
            else        { sp1.x += v * asv[ni]; sp1.y += v * adv[ni]; }
        }
        #pragma unroll
        for (int msk = 1; msk < 16; msk <<= 1) {
            sp0.x += __shfl_xor(sp0.x, msk, 64); sp0.y += __shfl_xor(sp0.y, msk, 64);
            sp1.x += __shfl_xor(sp1.x, msk, 64); sp1.y += __shfl_xor(sp1.y, msk, 64);
        }
        if (lr == 0) { red[row][cw * 2] = sp0; red[row][cw * 2 + 1] = sp1; }
    }
    __syncthreads();
    #pragma unroll
    for (int r = 0; r < 4; ++r) {
        const int grow = m0 + rw * 16 + lg * 4 + r;
        const int node = (grow & 7) * 1024 + (grow >> 3);
        #pragma unroll
        for (int ni = 0; ni < 4; ++ni)
            XH[(size_t)node * 256 + col[ni]] = f2bf(acc2[ni][r]);
    }
    for (int idx = tid; idx < 32 * 8; idx += 512) {
        const int row = idx >> 3, h = idx & 7;
        const int grow = m0 + row;
        const int node = (grow & 7) * 1024 + (grow >> 3);
        asrc[(size_t)node * 8 + h] = red[row][h].x;
        adst[(size_t)node * 8 + h] = red[row][h].y;
    }
}

// -------------------- fused GEMM + LN (final): out = LN(X2 + Hb@W2^T + b) --------------------
__global__ __launch_bounds__(512) void gemm_ln2(const u16* __restrict__ A, int lda,
                                                const u16* __restrict__ W, int ldw, int Ksz,
                                                const float* __restrict__ bias,
                                                const float* __restrict__ resid,
                                                const float* __restrict__ gamma,
                                                const float* __restrict__ beta,
                                                float* __restrict__ outf)
{
    constexpr int BM = 32;
    const int tid = threadIdx.x;
    __shared__ u16 As[2][BM * 32];
    __shared__ u16 Bs[2][256 * 32];
    __shared__ float2 red[BM][8];
    const int m0 = blockIdx.x * BM;
    const int lane = tid & 63, w = tid >> 6;
    const int rw = w >> 2, cw = w & 3;
    const int lr = lane & 15, lg = lane >> 4;

    f32x4 acc[4] = {};

    auto stage = [&](int buf, int k0) {
        #pragma unroll
        for (int j = 0; j < 2; ++j) {
            const int idx = tid + j * 512;
            gload16(W + (size_t)(idx >> 2) * ldw + (idx & 3) * 8 + k0, &Bs[buf][idx * 8]);
        }
        if (tid < BM * 4)
            gload16(A + (size_t)(m0 + (tid >> 2)) * lda + (tid & 3) * 8 + k0, &As[buf][tid * 8]);
    };
    stage(0, 0);
    __syncthreads();
    const int nt = Ksz >> 5;
    int cur = 0;
    for (int kt = 0; kt < nt; ++kt) {
        if (kt + 1 < nt) stage(cur ^ 1, (kt + 1) << 5);
        bf16x8 af = *(const bf16x8*)&As[cur][(rw * 16 + lr) * 32 + lg * 8];
        bf16x8 bg[4];
        #pragma unroll
        for (int i = 0; i < 4; ++i)  bg[i] = *(const bf16x8*)&Bs[cur][(cw * 64 + i * 16 + lr) * 32 + lg * 8];
        #pragma unroll
        for (int ni = 0; ni < 4; ++ni)
            acc[ni] = __builtin_amdgcn_mfma_f32_16x16x32_bf16(af, bg[ni], acc[ni], 0, 0, 0);
        __syncthreads();
        cur ^= 1;
    }
    int col[4]; float gam[4], bet[4], bv[4];
    #pragma unroll
    for (int ni = 0; ni < 4; ++ni) {
        col[ni] = cw * 64 + ni * 16 + lr;
        gam[ni] = gamma[col[ni]]; bet[ni] = beta[col[ni]]; bv[ni] = bias[col[ni]];
    }
    #pragma unroll
    for (int r = 0; r < 4; ++r) {
        const int row = rw * 16 + lg * 4 + r;
        const int grow = m0 + row;
        float s1 = 0.f, s2 = 0.f;
        #pragma unroll
        for (int ni = 0; ni < 4; ++ni) {
            float v = acc[ni][r] + bv[ni] + resid[(size_t)grow * 256 + col[ni]];
            acc[ni][r] = v;
            s1 += v; s2 += v * v;
        }
        #pragma unroll
        for (int msk = 1; msk < 16; msk <<= 1) { s1 += __shfl_xor(s1, msk, 64); s2 += __shfl_xor(s2, msk, 64); }
        if (lr == 0) red[row][cw] = (float2){s1, s2};
    }
    __syncthreads();
    #pragma unroll
    for (int r = 0; r < 4; ++r) {
        const int row = rw * 16 + lg * 4 + r;
        const int grow = m0 + row;
        const float2 t0 = red[row][0], t1 = red[row][1], t2 = red[row][2], t3 = red[row][3];
        const float mean = (t0.x + t1.x + t2.x + t3.x) * (1.f / 256.f);
        const float var  = (t0.y + t1.y + t2.y + t3.y) * (1.f / 256.f) - mean * mean;
        const float rs = rsqrtf(var + 1e-5f);
        #pragma unroll
        for (int ni = 0; ni < 4; ++ni)
            outf[(size_t)grow * 256 + col[ni]] = (acc[ni][r] - mean) * rs * gam[ni] + bet[ni];
    }
}

// -------------------- GAT gather + residual + LN2: 2 waves/dst, dual-edge lane split, no max,
// src indices preloaded to registers and distributed via shfl (removes one latency level) ----------
__global__ __launch_bounds__(256) void gat_gather_ln(const int* __restrict__ sorted, const int* __restrict__ offset,
                                                     const float* __restrict__ asrc, const float* __restrict__ adst,
                                                     const u16* __restrict__ xh,
                                                     const float* __restrict__ X1f, const float* __restrict__ gb,
                                                     const float* __restrict__ g2, const float* __restrict__ be2,
                                                     const float* __restrict__ cond,
                                                     float* __restrict__ X2f, u16* __restrict__ X2pad)
{
    const int wid = threadIdx.x >> 6, lane = threadIdx.x & 63;
    const int pair = wid >> 1, half = wid & 1;
    const int dst = blockIdx.x * 2 + pair;
    const int sub = lane >> 5, l32 = lane & 31;
    const int h = l32 >> 2;                     // head of dims 8*l32..+7
    const float ad = adst[dst * 8 + h];
    const int beg = offset[dst], end = offset[dst + 1];
    const int mid = beg + ((end - beg + 1) >> 1);
    const int b0 = half ? mid : beg;
    const int b1 = half ? end : mid;

    __shared__ float szs[2][8];
    __shared__ __align__(16) float sa[2][32][8];

    // preload up to 32 src indices per edge-stream: lane (sub, l32) loads its stream's l32-th index
    int pidx = b0 + sub * 0 + 2 * l32;          // stream stride 2 starting at b0+sub
    pidx = b0 + sub + 2 * l32;
    int pre = sorted[pidx < ET_ ? pidx : ET_ - 1];

    float z = 0.f;
    float a[8] = {};
    int it = 0;
    #pragma unroll 4
    for (int i = b0 + sub; i < b1; i += 2, ++it) {
        const int src = (it < 32) ? __shfl(pre, sub * 32 + it, 64) : sorted[i];
        float e = asrc[src * 8 + h] + ad;
        e = fmaxf(e, 0.2f * e);
        const float p = __expf(e);
        z += p;
        const uint4 xv = *(const uint4*)&xh[(size_t)src * 256 + l32 * 8];
        a[0] += p * __uint_as_float(xv.x << 16);
        a[1] += p * __uint_as_float(xv.x & 0xffff0000u);
        a[2] += p * __uint_as_float(xv.y << 16);
        a[3] += p * __uint_as_float(xv.y & 0xffff0000u);
        a[4] += p * __uint_as_float(xv.z << 16);
        a[5] += p * __uint_as_float(xv.z & 0xffff0000u);
        a[6] += p * __uint_as_float(xv.w << 16);
        a[7] += p * __uint_as_float(xv.w & 0xffff0000u);
    }
    // combine the two 32-lane sub-halves
    z += __shfl_xor(z, 32, 64);
    #pragma unroll
    for (int j = 0; j < 8; ++j) a[j] += __shfl_xor(a[j], 32, 64);
    // cross-wave merge (half 1 -> LDS)
    if (half && sub == 0) {
        if ((l32 & 3) == 0) szs[pair][h] = z;
        *(f32x4*)&sa[pair][l32][0] = (f32x4){a[0], a[1], a[2], a[3]};
        *(f32x4*)&sa[pair][l32][4] = (f32x4){a[4], a[5], a[6], a[7]};
    }
    __syncthreads();
    if (half) return;
    const float zt = z + szs[pair][h];
    const float inv = 1.f / zt;
    const int row = (dst & 1023) * 8 + (dst >> 10);    // dst = b*1024 + s -> row = s*8 + b
    float v[8];
    {
        const f32x4 x0 = *(const f32x4*)&X1f[(size_t)row * 256 + l32 * 8];
        const f32x4 x1 = *(const f32x4*)&X1f[(size_t)row * 256 + l32 * 8 + 4];
        const f32x4 gb0 = *(const f32x4*)&gb[l32 * 8];
        const f32x4 gb1 = *(const f32x4*)&gb[l32 * 8 + 4];
        const f32x4 m0 = *(const f32x4*)&sa[pair][l32][0];
        const f32x4 m1 = *(const f32x4*)&sa[pair][l32][4];
        #pragma unroll
        for (int j = 0; j < 4; ++j) {
            v[j]     = x0[j] + (a[j] + m0[j]) * inv + gb0[j];
            v[4 + j] = x1[j] + (a[4 + j] + m1[j]) * inv + gb1[j];
        }
    }
    float s1 = 0.f, s2 = 0.f;
    #pragma unroll
    for (int j = 0; j < 8; ++j) { s1 += v[j]; s2 += v[j] * v[j]; }
    #pragma unroll
    for (int msk = 1; msk < 32; msk <<= 1) { s1 += __shfl_xor(s1, msk, 64); s2 += __shfl_xor(s2, msk, 64); }
    const float mean = s1 * (1.f / 256.f);
    const float var = s2 * (1.f / 256.f) - mean * mean;
    const float rs = rsqrtf(var + 1e-5f);
    if (sub == 0) {
        const f32x4 gg0 = *(const f32x4*)&g2[l32 * 8];
        const f32x4 gg1 = *(const f32x4*)&g2[l32 * 8 + 4];
        const f32x4 be0 = *(const f32x4*)&be2[l32 * 8];
        const f32x4 be1 = *(const f32x4*)&be2[l32 * 8 + 4];
        f32x4 o0, o1;
        u16 ob[8];
        #pragma unroll
        for (int j = 0; j < 4; ++j) {
            o0[j] = (v[j] - mean) * rs * gg0[j] + be0[j];
            o1[j] = (v[4 + j] - mean) * rs * gg1[j] + be1[j];
            ob[j] = f2bf(o0[j]); ob[4 + j] = f2bf(o1[j]);
        }
        *(f32x4*)&X2f[(size_t)row * 256 + l32 * 8]     = o0;
        *(f32x4*)&X2f[(size_t)row * 256 + l32 * 8 + 4] = o1;
        *(uint4*)&X2pad[(size_t)row * 288 + l32 * 8] = *(uint4*)ob;
        if (l32 < 8) {
            u16 zz[4] = {0, 0, 0, 0};
            if (l32 == 0) zz[0] = f2bf(cond[row]);
            *(uint2*)&X2pad[(size_t)row * 288 + 256 + l32 * 4] = *(uint2*)zz;
        }
    }
}

// -------------------- FFN w1 GEMM (128x128 tile) --------------------
__global__ __launch_bounds__(256) void gemm_w1(const u16* __restrict__ A,
                                               const u16* __restrict__ W,
                                               const float* __restrict__ bias,
                                               u16* __restrict__ Cv)
{
    __shared__ u16 As[2][128 * 32];
    __shared__ u16 Bs[2][128 * 32];
    const int tid = threadIdx.x;
    const int m0 = blockIdx.y * 128, n0 = blockIdx.x * 128;
    const int lane = tid & 63, w = tid >> 6;
    const int wm = w >> 1, wn = w & 1;
    const int lr = lane & 15, lg = lane >> 4;

    f32x4 acc[4][4] = {};

    const u16* Ag = A + (size_t)(m0 + (tid >> 2)) * 288 + (tid & 3) * 8;
    const u16* Wg = W + (size_t)(n0 + (tid >> 2)) * 288 + (tid & 3) * 8;

    auto stage = [&](int buf, int k0) {
        gload16(Ag + k0,                    &As[buf][tid * 8]);
        gload16(Ag + (size_t)64 * 288 + k0, &As[buf][64 * 32 + tid * 8]);
        gload16(Wg + k0,                    &Bs[buf][tid * 8]);
        gload16(Wg + (size_t)64 * 288 + k0, &Bs[buf][64 * 32 + tid * 8]);
    };
    stage(0, 0);
    __syncthreads();
    int cur = 0;
    for (int kt = 0; kt < 9; ++kt) {
        if (kt + 1 < 9) stage(cur ^ 1, (kt + 1) << 5);
        bf16x8 af[4], bg[4];
        #pragma unroll
        for (int i = 0; i < 4; ++i) {
            af[i] = *(const bf16x8*)&As[cur][(wm * 64 + i * 16 + lr) * 32 + lg * 8];
            bg[i] = *(const bf16x8*)&Bs[cur][(wn * 64 + i * 16 + lr) * 32 + lg * 8];
        }
        #pragma unroll
        for (int mi = 0; mi < 4; ++mi)
            #pragma unroll
            for (int ni = 0; ni < 4; ++ni)
                acc[mi][ni] = __builtin_amdgcn_mfma_f32_16x16x32_bf16(af[mi], bg[ni], acc[mi][ni], 0, 0, 0);
        __syncthreads();
        cur ^= 1;
    }
    #pragma unroll
    for (int mi = 0; mi < 4; ++mi)
        #pragma unroll
        for (int ni = 0; ni < 4; ++ni) {
            const int col = n0 + wn * 64 + ni * 16 + lr;
            const float bv = bias[col];
            #pragma unroll
            for (int r = 0; r < 4; ++r) {
                const int row = m0 + wm * 64 + mi * 16 + lg * 4 + r;
                Cv[(size_t)row * 1024 + col] = f2bf(fmaxf(acc[mi][ni][r] + bv, 0.f));
            }
        }
}

extern "C" void kernel_launch(void* const* d_in, const int* in_sizes, int n_in,
                              void* d_out, int out_size, void* d_ws, size_t ws_size,
                              hipStream_t stream)
{
    const float* x          = (const float*)d_in[0];
    const float* condition  = (const float*)d_in[1];
    const float* in_proj_w  = (const float*)d_in[2];
    const float* in_proj_b  = (const float*)d_in[3];
    const float* out_proj_w = (const float*)d_in[4];
    const float* out_proj_b = (const float*)d_in[5];
    const float* g1         = (const float*)d_in[6];
    const float* be1        = (const float*)d_in[7];
    const float* g2         = (const float*)d_in[8];
    const float* be2        = (const float*)d_in[9];
    const float* g3         = (const float*)d_in[10];
    const float* be3        = (const float*)d_in[11];
    const float* lin_w      = (const float*)d_in[12];
    const float* att_src    = (const float*)d_in[13];
    const float* att_dst    = (const float*)d_in[14];
    const float* gat_bias   = (const float*)d_in[15];
    const float* w1         = (const float*)d_in[16];
    const float* bf1        = (const float*)d_in[17];
    const float* w2         = (const float*)d_in[18];
    const float* bf2        = (const float*)d_in[19];
    const int*   edge_index = (const int*)d_in[20];
    float* out = (float*)d_out;

    char* ws = (char*)d_ws;
    u16*   QKV    = (u16*)(ws + 0);              // 12.6MB [QKV gemm, attn]
    u16*   Hb     = (u16*)(ws + 0);              // 16MB   [w1 gemm, w2 gemm] (QKV dead)
    u16*   CTX    = (u16*)(ws + 16777216);       // 4MB    [attn, ln1-gemm]
    u16*   XH     = (u16*)(ws + 25165824);       // 4MB    [ln1-gemm, gather]
    float* X1f    = (float*)(ws + 29360128);     // 8MB    [ln1-gemm, gather]
    float* X2f    = (float*)(ws + 37748736);     // 8MB    [gather, w2-gemm]
    u16*   X2pad  = (u16*)(ws + 46137344);       // 4.72MB [gather, w1 gemm]
    u16*   Xbf    = (u16*)(ws + 50855936);       // 4MB    [convert, QKV gemm]
    float* ASRC   = (float*)(ws + 55050240);     // 256KB
    float* ADST   = (float*)(ws + 55312384);     // 256KB
    u16*   W_inp  = (u16*)(ws + 55574528);       // 393,216
    u16*   W_out  = (u16*)(ws + 55967744);       // 131,072
    u16*   W_lin  = (u16*)(ws + 56098816);       // 131,072
    u16*   W_w1   = (u16*)(ws + 56229888);       // 589,824 (1024 x 288)
    u16*   W_w2   = (u16*)(ws + 56819712);       // 524,288
    int*   COUNT  = (int*)(ws + 57344000);       // 32,768
    int*   OFFSET = (int*)(ws + 57376768);       // 36,864 (8193 used)
    int*   CURSOR = (int*)(ws + 57413632);       // 32,768
    int*   SORTED = (int*)(ws + 57446400);       // 1,081,344 -> ends 58,527,744

    // 1. conversions (x vectorized) + zero sort counters
    convert_all<<<5568, 256, 0, stream>>>(x, in_proj_w, out_proj_w, lin_w, w1, w2,
                                          Xbf, W_inp, W_out, W_lin, W_w1, W_w2, COUNT, CURSOR);
    // 2. QKV GEMM (768 blocks) + edge histogram (1056 blocks)
    gemm_qkv_hist<<<1824, 256, 0, stream>>>(Xbf, W_inp, in_proj_b, QKV, edge_index, COUNT);
    // 3. flash attention (512 blocks, double-buffered, no-max softmax) + offset scan (1 block)
    attn_mfma<<<513, 512, 0, stream>>>(QKV, CTX, COUNT, OFFSET);
    // 4. X1 = LN(x + CTX@Wo^T + b) -> X1f; chained XH = X1 @ Wl^T -> XH + scores (256 blocks)
    //    + edge scatter (528 blocks)
    gemm_ln0_xh<<<784, 512, 0, stream>>>(CTX, W_out, W_lin, out_proj_b, x, g1, be1,
                                         att_src, att_dst, X1f, XH, ASRC, ADST,
                                         edge_index, OFFSET, CURSOR, SORTED);
    // 5. gather + residual + LN2 -> X2f f32 + X2pad bf16 (K=288 w/ cond col)
    gat_gather_ln<<<4096, 256, 0, stream>>>(SORTED, OFFSET, ASRC, ADST, XH,
                                            X1f, gat_bias, g2, be2, condition, X2f, X2pad);
    // 6. H = relu(X2pad @ W_w1^T + bf1)
    gemm_w1<<<dim3(8, 64), 256, 0, stream>>>(X2pad, W_w1, bf1, Hb);
    // 7. out = LN(X2 + Hb@W_w2^T + bf2)
    gemm_ln2<<<256, 512, 0, stream>>>(Hb, 1024, W_w2, 1024, 1024, bf2, X2f, g3, be3, out);
}

// Round 19
// 132.375 us; speedup vs baseline: 1.0680x; 1.0078x over previous
//
#include <hip/hip_runtime.h>
#include <hip/hip_bf16.h>

// Problem constants
#define S_ 1024
#define B_ 8
#define D_ 256
#define H_ 8
#define DH_ 32
#define N_ 8192           // S*B nodes
#define E_ 262144
#define ET_ 270336        // E + N (self loops)

typedef unsigned short u16;
typedef float f32x4 __attribute__((ext_vector_type(4)));
typedef __bf16 bf16x8 __attribute__((ext_vector_type(8)));
typedef short s16x4 __attribute__((ext_vector_type(4)));

#define QK_SCALE 0.17677669529663687f  // 1/sqrt(32)

// f32 -> bf16 (RNE)
__device__ inline u16 f2bf(float v) {
    unsigned int u = __float_as_uint(v);
    u = (u + 0x7fffu + ((u >> 16) & 1u)) >> 16;
    return (u16)u;
}
__device__ inline float bf2f(u16 u) { return __uint_as_float(((unsigned int)u) << 16); }

// pack two f32 -> two bf16 (truncation) in one v_perm
__device__ inline unsigned int pack_trunc(float lo, float hi) {
    return __builtin_amdgcn_perm(__float_as_uint(hi), __float_as_uint(lo), 0x07060302u);
}

// async global->LDS 16B
__device__ inline void gload16(const u16* g, u16* l) {
    __builtin_amdgcn_global_load_lds((const __attribute__((address_space(1))) unsigned int*)g,
                                     (__attribute__((address_space(3))) unsigned int*)l, 16, 0, 0);
}

// K=16 bf16 MFMA
__device__ inline f32x4 mfma16bf(s16x4 a, s16x4 b, f32x4 c) {
#if __has_builtin(__builtin_amdgcn_mfma_f32_16x16x16bf16_1k)
    return __builtin_amdgcn_mfma_f32_16x16x16bf16_1k(a, b, c, 0, 0, 0);
#else
    asm volatile("v_mfma_f32_16x16x16_bf16 %0, %1, %2, %0" : "+v"(c) : "v"(a), "v"(b));
    return c;
#endif
}

// -------------------- fused conversions (x vectorized 4x) + zero-init of sort counters --------------------
__global__ __launch_bounds__(256) void convert_all(const float* __restrict__ x,  const float* __restrict__ wi,
                                                   const float* __restrict__ wo, const float* __restrict__ wl,
                                                   const float* __restrict__ w1, const float* __restrict__ w2,
                                                   u16* __restrict__ Xbf, u16* __restrict__ Wi, u16* __restrict__ Wo,
                                                   u16* __restrict__ Wl, u16* __restrict__ W1, u16* __restrict__ W2,
                                                   int* __restrict__ count, int* __restrict__ cursor)
{
    const int idx = blockIdx.x * 256 + threadIdx.x;
    const int C0 = 524288;             // x as float4 units: 8192*256/4
    const int C1 = C0 + 196608;        // in_proj 768*256
    const int C2 = C1 + 65536;         // out_proj
    const int C3 = C2 + 65536;         // lin
    const int C4 = C3 + 294912;        // w1 padded 1024*288 (kin 257)
    const int C5 = C4 + 262144;        // w2 256*1024
    const int C6 = C5 + 16384;         // zero COUNT(8192) + CURSOR(8192)
    if (idx < C0) {
        const float4 v = *(const float4*)&x[(size_t)idx * 4];
        u16 o[4] = {f2bf(v.x), f2bf(v.y), f2bf(v.z), f2bf(v.w)};
        *(uint2*)&Xbf[(size_t)idx * 4] = *(uint2*)o;
    }
    else if (idx < C1) { int i = idx - C0; Wi[i] = f2bf(wi[i]); }
    else if (idx < C2) { int i = idx - C1; Wo[i] = f2bf(wo[i]); }
    else if (idx < C3) { int i = idx - C2; Wl[i] = f2bf(wl[i]); }
    else if (idx < C4) { int i = idx - C3; int r = i / 288, k = i - r * 288;
                         W1[i] = (k < 257) ? f2bf(w1[r * 257 + k]) : (u16)0; }
    else if (idx < C5) { int i = idx - C4; W2[i] = f2bf(w2[i]); }
    else if (idx < C6) { int i = idx - C5; if (i < 8192) count[i] = 0; else cursor[i - 8192] = 0; }
}

// -------------------- QKV GEMM (BN=64) + edge histogram in extra blocks --------------------
// Q/K planes: [b][h][key][dim]. V plane: [b][h][key>>2][dim][key&3]  (transpose-ready for attn PV).
__global__ __launch_bounds__(256) void gemm_qkv_hist(const u16* __restrict__ A,
                                                     const u16* __restrict__ W,
                                                     const float* __restrict__ bias,
                                                     u16* __restrict__ Cv,
                                                     const int* __restrict__ ei, int* __restrict__ count)
{
    const int tid = threadIdx.x;
    if (blockIdx.x >= 768) {               // histogram blocks (COUNT zeroed by convert_all)
        const int e = (blockIdx.x - 768) * 256 + tid;   // 1056*256 == ET_
        const int dst = (e < E_) ? ei[E_ + e] : e - E_;
        atomicAdd(&count[dst], 1);
        return;
    }
    __shared__ u16 As[2][128 * 32];
    __shared__ u16 Bs[2][64 * 32];
    const int m0 = (blockIdx.x / 12) * 128, n0 = (blockIdx.x % 12) * 64;
    const int lane = tid & 63, w = tid >> 6;
    const int wm = w >> 1, wn = w & 1;
    const int lr = lane & 15, lg = lane >> 4;

    f32x4 acc[4][2] = {};

    const u16* Ag = A + (size_t)(m0 + (tid >> 2)) * 256 + (tid & 3) * 8;
    const u16* Wg = W + (size_t)(n0 + (tid >> 2)) * 256 + (tid & 3) * 8;

    auto stage = [&](int buf, int k0) {
        gload16(Ag + k0,                    &As[buf][tid * 8]);
        gload16(Ag + (size_t)64 * 256 + k0, &As[buf][64 * 32 + tid * 8]);
        gload16(Wg + k0,                    &Bs[buf][tid * 8]);
    };
    stage(0, 0);
    __syncthreads();
    int cur = 0;
    for (int kt = 0; kt < 8; ++kt) {
        if (kt + 1 < 8) stage(cur ^ 1, (kt + 1) << 5);
        bf16x8 af[4], bg[2];
        #pragma unroll
        for (int i = 0; i < 4; ++i) af[i] = *(const bf16x8*)&As[cur][(wm * 64 + i * 16 + lr) * 32 + lg * 8];
        #pragma unroll
        for (int i = 0; i < 2; ++i) bg[i] = *(const bf16x8*)&Bs[cur][(wn * 32 + i * 16 + lr) * 32 + lg * 8];
        #pragma unroll
        for (int mi = 0; mi < 4; ++mi)
            #pragma unroll
            for (int ni = 0; ni < 2; ++ni)
                acc[mi][ni] = __builtin_amdgcn_mfma_f32_16x16x32_bf16(af[mi], bg[ni], acc[mi][ni], 0, 0, 0);
        __syncthreads();
        cur ^= 1;
    }
    #pragma unroll
    for (int mi = 0; mi < 4; ++mi)
        #pragma unroll
        for (int ni = 0; ni < 2; ++ni) {
            const int col = n0 + wn * 32 + ni * 16 + lr;
            const float bv = bias[col];
            const int part = col >> 8, hh = (col >> 5) & 7, dh = col & 31;
            #pragma unroll
            for (int r = 0; r < 4; ++r) {
                const int row = m0 + wm * 64 + mi * 16 + lg * 4 + r;
                const int ss = row >> 3, bb = row & 7;
                const size_t pbase = ((size_t)((part * 8 + bb) * 8 + hh)) * 32768;
                const u16 val = f2bf(acc[mi][ni][r] + bv);
                if (part == 2) Cv[pbase + (size_t)(ss >> 2) * 128 + dh * 4 + (ss & 3)] = val;
                else           Cv[pbase + (size_t)ss * 32 + dh] = val;
            }
        }
}

// -------------------- MFMA flash attention (dbuf, no-max softmax, V via gload16 interleaved) + scan --------
__global__ __launch_bounds__(512) void attn_mfma(const u16* __restrict__ qkv, u16* __restrict__ ctx,
                                                 const int* __restrict__ count, int* __restrict__ offset)
{
    const int tid = threadIdx.x;
    if (blockIdx.x == 512) {               // prefix-scan block (COUNT complete: previous dispatch)
        __shared__ int s[512];
        const int base = tid * 16;
        int c[16]; int sum = 0;
        #pragma unroll
        for (int i = 0; i < 16; ++i) { c[i] = count[base + i]; sum += c[i]; }
        s[tid] = sum; __syncthreads();
        for (int off = 1; off < 512; off <<= 1) {
            int add = (tid >= off) ? s[tid - off] : 0;
            __syncthreads();
            s[tid] += add;
            __syncthreads();
        }
        int run = (tid == 0) ? 0 : s[tid - 1];
        #pragma unroll
        for (int i = 0; i < 16; ++i) { offset[base + i] = run; run += c[i]; }
        if (tid == 511) offset[8192] = run;   // = ET_
        return;
    }
    const int qt = blockIdx.x & 7, bh = blockIdx.x >> 3;
    const int b = bh >> 3, h = bh & 7;
    const int lane = tid & 63, w = tid >> 6;
    const int c = lane & 15, g = lane >> 4;

    __shared__ __align__(16) u16 Ks[2][128][40];
    __shared__ __align__(16) u16 Vs[2][4096];   // [grp 32][dim 32][key&3 4] per chunk

    const size_t plane = (size_t)(b * 8 + h) * 32768;
    const int q0 = qt * 128 + w * 16;
    const bf16x8 qf = *(const bf16x8*)&qkv[plane + (size_t)(q0 + c) * 32 + g * 8];
    const u16* kbase = qkv + 2097152 + plane;       // K plane [key][dim]
    const u16* vbase = qkv + 2 * 2097152 + plane;   // V plane [key>>2][dim][key&3]

    auto stage = [&](int buf, int kt) {
        const int r = tid >> 2, c0 = (tid & 3) * 8;
        const u16* kp = kbase + (size_t)(kt * 128 + r) * 32 + c0;
        *(uint4*)&Ks[buf][r][c0] = *(const uint4*)kp;
        // V: lane-linear LDS dest == [grp=tid>>4][dims (2*tid)&31 .. +1][4 keys]
        gload16(vbase + (size_t)(kt * 32 + (tid >> 4)) * 128 + ((tid * 2) & 31) * 4, &Vs[buf][tid * 8]);
    };

    float l = 0.f;
    f32x4 o0 = {}, o1 = {};

    stage(0, 0);
    __syncthreads();
    int cur = 0;
    for (int kt = 0; kt < 8; ++kt) {
        if (kt + 1 < 8) stage(cur ^ 1, kt + 1);
        f32x4 sc[8];
        #pragma unroll
        for (int t = 0; t < 8; ++t) {
            const bf16x8 kf = *(const bf16x8*)&Ks[cur][t * 16 + c][g * 8];
            sc[t] = __builtin_amdgcn_mfma_f32_16x16x32_bf16(kf, qf, (f32x4){0.f, 0.f, 0.f, 0.f}, 0, 0, 0);
        }
        unsigned int pb[8][2];
        float ls = 0.f;
        #pragma unroll
        for (int t = 0; t < 8; ++t) {
            const float p0 = __expf(sc[t][0] * QK_SCALE);
            const float p1 = __expf(sc[t][1] * QK_SCALE);
            const float p2 = __expf(sc[t][2] * QK_SCALE);
            const float p3 = __expf(sc[t][3] * QK_SCALE);
            ls += (p0 + p1) + (p2 + p3);
            pb[t][0] = pack_trunc(p0, p1);
            pb[t][1] = pack_trunc(p2, p3);
        }
        l += ls;
        #pragma unroll
        for (int t = 0; t < 8; ++t) {
            union { unsigned int u[2]; s16x4 v; } pu;
            pu.u[0] = pb[t][0]; pu.u[1] = pb[t][1];
            const int vb = ((4 * t + g) * 32 + c) * 4;      // V[key=16t+4g+j][dim=c], j=0..3
            const s16x4 vf0 = *(const s16x4*)&Vs[cur][vb];
            const s16x4 vf1 = *(const s16x4*)&Vs[cur][vb + 64];  // dims 16+c
            o0 = mfma16bf(vf0, pu.v, o0);
            o1 = mfma16bf(vf1, pu.v, o1);
        }
        __syncthreads();
        cur ^= 1;
    }
    l += __shfl_xor(l, 16, 64);
    l += __shfl_xor(l, 32, 64);
    const float inv = 1.f / l;
    u16 ob[8];
    #pragma unroll
    for (int r = 0; r < 4; ++r) { ob[r] = f2bf(o0[r] * inv); ob[4 + r] = f2bf(o1[r] * inv); }
    const size_t obase = ((size_t)(q0 + c) * 8 + b) * 256 + h * 32 + g * 4;
    *(uint2*)&ctx[obase]      = *(uint2*)ob;
    *(uint2*)&ctx[obase + 16] = *(uint2*)(ob + 4);
}

// -------------------- fused out_proj GEMM + LN1 + chained XH GEMM + scores (+ scatter blocks) --------------------
__global__ __launch_bounds__(512) void gemm_ln0_xh(const u16* __restrict__ A,
                                                   const u16* __restrict__ Wo,
                                                   const u16* __restrict__ Wl,
                                                   const float* __restrict__ bias,
                                                   const float* __restrict__ resid,
                                                   const float* __restrict__ gamma,
                                                   const float* __restrict__ beta,
                                                   const float* __restrict__ att_s,
                                                   const float* __restrict__ att_d,
                                                   float* __restrict__ X1f,
                                                   u16* __restrict__ XH,
                                                   float* __restrict__ asrc,
                                                   float* __restrict__ adst,
                                                   const int* __restrict__ ei,
                                                   const int* __restrict__ offset,
                                                   int* __restrict__ cursor,
                                                   int* __restrict__ sorted)
{
    const int tid = threadIdx.x;
    if (blockIdx.x >= 256) {               // scatter blocks
        const int e = (blockIdx.x - 256) * 512 + tid;   // 528*512 == ET_
        int src, dst;
        if (e < E_) { src = ei[e]; dst = ei[E_ + e]; }
        else        { src = dst = e - E_; }
        const int pos = offset[dst] + atomicAdd(&cursor[dst], 1);
        sorted[pos] = src;
        return;
    }
    __shared__ u16 As[2][32 * 32];
    __shared__ u16 Bs[2][256 * 32];
    __shared__ float2 red[32][8];
    __shared__ __align__(16) u16 X1s[32][264];
    const int m0 = blockIdx.x * 32;
    const int lane = tid & 63, w = tid >> 6;
    const int rw = w >> 2, cw = w & 3;
    const int lr = lane & 15, lg = lane >> 4;

    auto stageW = [&](const u16* W, int buf, int k0) {
        #pragma unroll
        for (int j = 0; j < 2; ++j) {
            const int idx = tid + j * 512;
            gload16(W + (size_t)(idx >> 2) * 256 + (idx & 3) * 8 + k0, &Bs[buf][idx * 8]);
        }
    };
    auto stageA = [&](int buf, int k0) {
        if (tid < 128)
            gload16(A + (size_t)(m0 + (tid >> 2)) * 256 + (tid & 3) * 8 + k0, &As[buf][tid * 8]);
    };

    // ---- GEMM1: CTX @ Wo^T ----
    f32x4 acc[4] = {};
    stageW(Wo, 0, 0); stageA(0, 0);
    __syncthreads();
    int cur = 0;
    for (int kt = 0; kt < 8; ++kt) {
        if (kt + 1 < 8) { stageW(Wo, cur ^ 1, (kt + 1) << 5); stageA(cur ^ 1, (kt + 1) << 5); }
        const bf16x8 af = *(const bf16x8*)&As[cur][(rw * 16 + lr) * 32 + lg * 8];
        bf16x8 bg[4];
        #pragma unroll
        for (int i = 0; i < 4; ++i)  bg[i] = *(const bf16x8*)&Bs[cur][(cw * 64 + i * 16 + lr) * 32 + lg * 8];
        #pragma unroll
        for (int ni = 0; ni < 4; ++ni)
            acc[ni] = __builtin_amdgcn_mfma_f32_16x16x32_bf16(af, bg[ni], acc[ni], 0, 0, 0);
        __syncthreads();
        cur ^= 1;
    }
    // ---- epilogue1 ----
    int col[4]; float gam[4], bet[4], bv[4];
    #pragma unroll
    for (int ni = 0; ni < 4; ++ni) {
        col[ni] = cw * 64 + ni * 16 + lr;
        gam[ni] = gamma[col[ni]]; bet[ni] = beta[col[ni]]; bv[ni] = bias[col[ni]];
    }
    #pragma unroll
    for (int r = 0; r < 4; ++r) {
        const int row = rw * 16 + lg * 4 + r;
        const int grow = m0 + row;
        float s1 = 0.f, s2 = 0.f;
        #pragma unroll
        for (int ni = 0; ni < 4; ++ni) {
            float v = acc[ni][r] + bv[ni] + resid[(size_t)grow * 256 + col[ni]];
            acc[ni][r] = v;
            s1 += v; s2 += v * v;
        }
        #pragma unroll
        for (int msk = 1; msk < 16; msk <<= 1) { s1 += __shfl_xor(s1, msk, 64); s2 += __shfl_xor(s2, msk, 64); }
        if (lr == 0) red[row][cw] = (float2){s1, s2};
    }
    __syncthreads();
    #pragma unroll
    for (int r = 0; r < 4; ++r) {
        const int row = rw * 16 + lg * 4 + r;
        const int grow = m0 + row;
        const float2 t0 = red[row][0], t1 = red[row][1], t2 = red[row][2], t3 = red[row][3];
        const float mean = (t0.x + t1.x + t2.x + t3.x) * (1.f / 256.f);
        const float var  = (t0.y + t1.y + t2.y + t3.y) * (1.f / 256.f) - mean * mean;
        const float rs = rsqrtf(var + 1e-5f);
        #pragma unroll
        for (int ni = 0; ni < 4; ++ni) {
            const float o = (acc[ni][r] - mean) * rs * gam[ni] + bet[ni];
            X1f[(size_t)grow * 256 + col[ni]] = o;
            X1s[row][col[ni]] = f2bf(o);
        }
    }
    // ---- GEMM2: XH = X1s @ Wl^T ----
    f32x4 acc2[4] = {};
    stageW(Wl, 0, 0);
    __syncthreads();
    cur = 0;
    for (int kt = 0; kt < 8; ++kt) {
        if (kt + 1 < 8) stageW(Wl, cur ^ 1, (kt + 1) << 5);
        const bf16x8 af = *(const bf16x8*)&X1s[rw * 16 + lr][kt * 32 + lg * 8];
        bf16x8 bg[4];
        #pragma unroll
        for (int i = 0; i < 4; ++i)  bg[i] = *(const bf16x8*)&Bs[cur][(cw * 64 + i * 16 + lr) * 32 + lg * 8];
        #pragma unroll
        for (int ni = 0; ni < 4; ++ni)
            acc2[ni] = __builtin_amdgcn_mfma_f32_16x16x32_bf16(af, bg[ni], acc2[ni], 0, 0, 0);
        __syncthreads();
        cur ^= 1;
    }
    // ---- epilogue2 ----
    float asv[4], adv[4];
    #pragma unroll
    for (int ni = 0; ni < 4; ++ni) { asv[ni] = att_s[col[ni]]; adv[ni] = att_d[col[ni]]; }
    #pragma unroll
    for (int r = 0; r < 4; ++r) {
        const int row = rw * 16 + lg * 4 + r;
        float2 sp0 = {0.f, 0.f}, sp1 = {0.f, 0.f};
        #pragma unroll
        for (int ni = 0; ni < 4; ++ni) {
            const float v = acc2[ni][r];
            if (ni < 2) { sp0.x += v * asv[ni]; sp0.y += v * adv[ni]; }
            else        { sp1.x += v * asv[ni]; sp1.y += v * adv[ni]; }
        }
        #pragma unroll
        for (int msk = 1; msk < 16; msk <<= 1) {
            sp0.x += __shfl_xor(sp0.x, msk, 64); sp0.y += __shfl_xor(sp0.y, msk, 64);
            sp1.x += __shfl_xor(sp1.x, msk, 64); sp1.y += __shfl_xor(sp1.y, msk, 64);
        }
        if (lr == 0) { red[row][cw * 2] = sp0; red[row][cw * 2 + 1] = sp1; }
    }
    __syncthreads();
    #pragma unroll
    for (int r = 0; r < 4; ++r) {
        const int grow = m0 + rw * 16 + lg * 4 + r;
        const int node = (grow & 7) * 1024 + (grow >> 3);
        #pragma unroll
        for (int ni = 0; ni < 4; ++ni)
            XH[(size_t)node * 256 + col[ni]] = f2bf(acc2[ni][r]);
    }
    for (int idx = tid; idx < 32 * 8; idx += 512) {
        const int row = idx >> 3, h = idx & 7;
        const int grow = m0 + row;
        const int node = (grow & 7) * 1024 + (grow >> 3);
        asrc[(size_t)node * 8 + h] = red[row][h].x;
        adst[(size_t)node * 8 + h] = red[row][h].y;
    }
}

// -------------------- fused GEMM + LN (final): out = LN(X2 + Hb@W2^T + b) --------------------
__global__ __launch_bounds__(512) void gemm_ln2(const u16* __restrict__ A, int lda,
                                                const u16* __restrict__ W, int ldw, int Ksz,
                                                const float* __restrict__ bias,
                                                const float* __restrict__ resid,
                                                const float* __restrict__ gamma,
                                                const float* __restrict__ beta,
                                                float* __restrict__ outf)
{
    constexpr int BM = 32;
    const int tid = threadIdx.x;
    __shared__ u16 As[2][BM * 32];
    __shared__ u16 Bs[2][256 * 32];
    __shared__ float2 red[BM][8];
    const int m0 = blockIdx.x * BM;
    const int lane = tid & 63, w = tid >> 6;
    const int rw = w >> 2, cw = w & 3;
    const int lr = lane & 15, lg = lane >> 4;

    f32x4 acc[4] = {};

    auto stage = [&](int buf, int k0) {
        #pragma unroll
        for (int j = 0; j < 2; ++j) {
            const int idx = tid + j * 512;
            gload16(W + (size_t)(idx >> 2) * ldw + (idx & 3) * 8 + k0, &Bs[buf][idx * 8]);
        }
        if (tid < BM * 4)
            gload16(A + (size_t)(m0 + (tid >> 2)) * lda + (tid & 3) * 8 + k0, &As[buf][tid * 8]);
    };
    stage(0, 0);
    __syncthreads();
    const int nt = Ksz >> 5;
    int cur = 0;
    for (int kt = 0; kt < nt; ++kt) {
        if (kt + 1 < nt) stage(cur ^ 1, (kt + 1) << 5);
        bf16x8 af = *(const bf16x8*)&As[cur][(rw * 16 + lr) * 32 + lg * 8];
        bf16x8 bg[4];
        #pragma unroll
        for (int i = 0; i < 4; ++i)  bg[i] = *(const bf16x8*)&Bs[cur][(cw * 64 + i * 16 + lr) * 32 + lg * 8];
        #pragma unroll
        for (int ni = 0; ni < 4; ++ni)
            acc[ni] = __builtin_amdgcn_mfma_f32_16x16x32_bf16(af, bg[ni], acc[ni], 0, 0, 0);
        __syncthreads();
        cur ^= 1;
    }
    int col[4]; float gam[4], bet[4], bv[4];
    #pragma unroll
    for (int ni = 0; ni < 4; ++ni) {
        col[ni] = cw * 64 + ni * 16 + lr;
        gam[ni] = gamma[col[ni]]; bet[ni] = beta[col[ni]]; bv[ni] = bias[col[ni]];
    }
    #pragma unroll
    for (int r = 0; r < 4; ++r) {
        const int row = rw * 16 + lg * 4 + r;
        const int grow = m0 + row;
        float s1 = 0.f, s2 = 0.f;
        #pragma unroll
        for (int ni = 0; ni < 4; ++ni) {
            float v = acc[ni][r] + bv[ni] + resid[(size_t)grow * 256 + col[ni]];
            acc[ni][r] = v;
            s1 += v; s2 += v * v;
        }
        #pragma unroll
        for (int msk = 1; msk < 16; msk <<= 1) { s1 += __shfl_xor(s1, msk, 64); s2 += __shfl_xor(s2, msk, 64); }
        if (lr == 0) red[row][cw] = (float2){s1, s2};
    }
    __syncthreads();
    #pragma unroll
    for (int r = 0; r < 4; ++r) {
        const int row = rw * 16 + lg * 4 + r;
        const int grow = m0 + row;
        const float2 t0 = red[row][0], t1 = red[row][1], t2 = red[row][2], t3 = red[row][3];
        const float mean = (t0.x + t1.x + t2.x + t3.x) * (1.f / 256.f);
        const float var  = (t0.y + t1.y + t2.y + t3.y) * (1.f / 256.f) - mean * mean;
        const float rs = rsqrtf(var + 1e-5f);
        #pragma unroll
        for (int ni = 0; ni < 4; ++ni)
            outf[(size_t)grow * 256 + col[ni]] = (acc[ni][r] - mean) * rs * gam[ni] + bet[ni];
    }
}

// -------------------- GAT gather + residual + LN2: 2 waves/dst, dual-edge lane split, no max,
// src indices preloaded to registers and distributed via shfl ----------
__global__ __launch_bounds__(256) void gat_gather_ln(const int* __restrict__ sorted, const int* __restrict__ offset,
                                                     const float* __restrict__ asrc, const float* __restrict__ adst,
                                                     const u16* __restrict__ xh,
                                                     const float* __restrict__ X1f, const float* __restrict__ gb,
                                                     const float* __restrict__ g2, const float* __restrict__ be2,
                                                     const float* __restrict__ cond,
                                                     float* __restrict__ X2f, u16* __restrict__ X2pad)
{
    const int wid = threadIdx.x >> 6, lane = threadIdx.x & 63;
    const int pair = wid >> 1, half = wid & 1;
    const int dst = blockIdx.x * 2 + pair;
    const int sub = lane >> 5, l32 = lane & 31;
    const int h = l32 >> 2;                     // head of dims 8*l32..+7
    const float ad = adst[dst * 8 + h];
    const int beg = offset[dst], end = offset[dst + 1];
    const int mid = beg + ((end - beg + 1) >> 1);
    const int b0 = half ? mid : beg;
    const int b1 = half ? end : mid;

    __shared__ float szs[2][8];
    __shared__ __align__(16) float sa[2][32][8];

    // preload up to 32 src indices per edge-stream
    int pidx = b0 + sub + 2 * l32;
    int pre = sorted[pidx < ET_ ? pidx : ET_ - 1];

    float z = 0.f;
    float a[8] = {};
    int it = 0;
    #pragma unroll 4
    for (int i = b0 + sub; i < b1; i += 2, ++it) {
        const int src = (it < 32) ? __shfl(pre, sub * 32 + it, 64) : sorted[i];
        float e = asrc[src * 8 + h] + ad;
        e = fmaxf(e, 0.2f * e);
        const float p = __expf(e);
        z += p;
        const uint4 xv = *(const uint4*)&xh[(size_t)src * 256 + l32 * 8];
        a[0] += p * __uint_as_float(xv.x << 16);
        a[1] += p * __uint_as_float(xv.x & 0xffff0000u);
        a[2] += p * __uint_as_float(xv.y << 16);
        a[3] += p * __uint_as_float(xv.y & 0xffff0000u);
        a[4] += p * __uint_as_float(xv.z << 16);
        a[5] += p * __uint_as_float(xv.z & 0xffff0000u);
        a[6] += p * __uint_as_float(xv.w << 16);
        a[7] += p * __uint_as_float(xv.w & 0xffff0000u);
    }
    z += __shfl_xor(z, 32, 64);
    #pragma unroll
    for (int j = 0; j < 8; ++j) a[j] += __shfl_xor(a[j], 32, 64);
    if (half && sub == 0) {
        if ((l32 & 3) == 0) szs[pair][h] = z;
        *(f32x4*)&sa[pair][l32][0] = (f32x4){a[0], a[1], a[2], a[3]};
        *(f32x4*)&sa[pair][l32][4] = (f32x4){a[4], a[5], a[6], a[7]};
    }
    __syncthreads();
    if (half) return;
    const float zt = z + szs[pair][h];
    const float inv = 1.f / zt;
    const int row = (dst & 1023) * 8 + (dst >> 10);    // dst = b*1024 + s -> row = s*8 + b
    float v[8];
    {
        const f32x4 x0 = *(const f32x4*)&X1f[(size_t)row * 256 + l32 * 8];
        const f32x4 x1 = *(const f32x4*)&X1f[(size_t)row * 256 + l32 * 8 + 4];
        const f32x4 gb0 = *(const f32x4*)&gb[l32 * 8];
        const f32x4 gb1 = *(const f32x4*)&gb[l32 * 8 + 4];
        const f32x4 m0 = *(const f32x4*)&sa[pair][l32][0];
        const f32x4 m1 = *(const f32x4*)&sa[pair][l32][4];
        #pragma unroll
        for (int j = 0; j < 4; ++j) {
            v[j]     = x0[j] + (a[j] + m0[j]) * inv + gb0[j];
            v[4 + j] = x1[j] + (a[4 + j] + m1[j]) * inv + gb1[j];
        }
    }
    float s1 = 0.f, s2 = 0.f;
    #pragma unroll
    for (int j = 0; j < 8; ++j) { s1 += v[j]; s2 += v[j] * v[j]; }
    #pragma unroll
    for (int msk = 1; msk < 32; msk <<= 1) { s1 += __shfl_xor(s1, msk, 64); s2 += __shfl_xor(s2, msk, 64); }
    const float mean = s1 * (1.f / 256.f);
    const float var = s2 * (1.f / 256.f) - mean * mean;
    const float rs = rsqrtf(var + 1e-5f);
    if (sub == 0) {
        const f32x4 gg0 = *(const f32x4*)&g2[l32 * 8];
        const f32x4 gg1 = *(const f32x4*)&g2[l32 * 8 + 4];
        const f32x4 be0 = *(const f32x4*)&be2[l32 * 8];
        const f32x4 be1 = *(const f32x4*)&be2[l32 * 8 + 4];
        f32x4 o0, o1;
        u16 ob[8];
        #pragma unroll
        for (int j = 0; j < 4; ++j) {
            o0[j] = (v[j] - mean) * rs * gg0[j] + be0[j];
            o1[j] = (v[4 + j] - mean) * rs * gg1[j] + be1[j];
            ob[j] = f2bf(o0[j]); ob[4 + j] = f2bf(o1[j]);
        }
        *(f32x4*)&X2f[(size_t)row * 256 + l32 * 8]     = o0;
        *(f32x4*)&X2f[(size_t)row * 256 + l32 * 8 + 4] = o1;
        *(uint4*)&X2pad[(size_t)row * 288 + l32 * 8] = *(uint4*)ob;
        if (l32 < 8) {
            u16 zz[4] = {0, 0, 0, 0};
            if (l32 == 0) zz[0] = f2bf(cond[row]);
            *(uint2*)&X2pad[(size_t)row * 288 + 256 + l32 * 4] = *(uint2*)zz;
        }
    }
}

// -------------------- FFN w1 GEMM (128x128 tile) --------------------
__global__ __launch_bounds__(256) void gemm_w1(const u16* __restrict__ A,
                                               const u16* __restrict__ W,
                                               const float* __restrict__ bias,
                                               u16* __restrict__ Cv)
{
    __shared__ u16 As[2][128 * 32];
    __shared__ u16 Bs[2][128 * 32];
    const int tid = threadIdx.x;
    const int m0 = blockIdx.y * 128, n0 = blockIdx.x * 128;
    const int lane = tid & 63, w = tid >> 6;
    const int wm = w >> 1, wn = w & 1;
    const int lr = lane & 15, lg = lane >> 4;

    f32x4 acc[4][4] = {};

    const u16* Ag = A + (size_t)(m0 + (tid >> 2)) * 288 + (tid & 3) * 8;
    const u16* Wg = W + (size_t)(n0 + (tid >> 2)) * 288 + (tid & 3) * 8;

    auto stage = [&](int buf, int k0) {
        gload16(Ag + k0,                    &As[buf][tid * 8]);
        gload16(Ag + (size_t)64 * 288 + k0, &As[buf][64 * 32 + tid * 8]);
        gload16(Wg + k0,                    &Bs[buf][tid * 8]);
        gload16(Wg + (size_t)64 * 288 + k0, &Bs[buf][64 * 32 + tid * 8]);
    };
    stage(0, 0);
    __syncthreads();
    int cur = 0;
    for (int kt = 0; kt < 9; ++kt) {
        if (kt + 1 < 9) stage(cur ^ 1, (kt + 1) << 5);
        bf16x8 af[4], bg[4];
        #pragma unroll
        for (int i = 0; i < 4; ++i) {
            af[i] = *(const bf16x8*)&As[cur][(wm * 64 + i * 16 + lr) * 32 + lg * 8];
            bg[i] = *(const bf16x8*)&Bs[cur][(wn * 64 + i * 16 + lr) * 32 + lg * 8];
        }
        #pragma unroll
        for (int mi = 0; mi < 4; ++mi)
            #pragma unroll
            for (int ni = 0; ni < 4; ++ni)
                acc[mi][ni] = __builtin_amdgcn_mfma_f32_16x16x32_bf16(af[mi], bg[ni], acc[mi][ni], 0, 0, 0);
        __syncthreads();
        cur ^= 1;
    }
    #pragma unroll
    for (int mi = 0; mi < 4; ++mi)
        #pragma unroll
        for (int ni = 0; ni < 4; ++ni) {
            const int col = n0 + wn * 64 + ni * 16 + lr;
            const float bv = bias[col];
            #pragma unroll
            for (int r = 0; r < 4; ++r) {
                const int row = m0 + wm * 64 + mi * 16 + lg * 4 + r;
                Cv[(size_t)row * 1024 + col] = f2bf(fmaxf(acc[mi][ni][r] + bv, 0.f));
            }
        }
}

extern "C" void kernel_launch(void* const* d_in, const int* in_sizes, int n_in,
                              void* d_out, int out_size, void* d_ws, size_t ws_size,
                              hipStream_t stream)
{
    const float* x          = (const float*)d_in[0];
    const float* condition  = (const float*)d_in[1];
    const float* in_proj_w  = (const float*)d_in[2];
    const float* in_proj_b  = (const float*)d_in[3];
    const float* out_proj_w = (const float*)d_in[4];
    const float* out_proj_b = (const float*)d_in[5];
    const float* g1         = (const float*)d_in[6];
    const float* be1        = (const float*)d_in[7];
    const float* g2         = (const float*)d_in[8];
    const float* be2        = (const float*)d_in[9];
    const float* g3         = (const float*)d_in[10];
    const float* be3        = (const float*)d_in[11];
    const float* lin_w      = (const float*)d_in[12];
    const float* att_src    = (const float*)d_in[13];
    const float* att_dst    = (const float*)d_in[14];
    const float* gat_bias   = (const float*)d_in[15];
    const float* w1         = (const float*)d_in[16];
    const float* bf1        = (const float*)d_in[17];
    const float* w2         = (const float*)d_in[18];
    const float* bf2        = (const float*)d_in[19];
    const int*   edge_index = (const int*)d_in[20];
    float* out = (float*)d_out;

    char* ws = (char*)d_ws;
    u16*   QKV    = (u16*)(ws + 0);              // 12.6MB [QKV gemm, attn]
    u16*   Hb     = (u16*)(ws + 0);              // 16MB   [w1 gemm, w2 gemm] (QKV dead)
    u16*   CTX    = (u16*)(ws + 16777216);       // 4MB    [attn, ln1-gemm]
    u16*   XH     = (u16*)(ws + 25165824);       // 4MB    [ln1-gemm, gather]
    float* X1f    = (float*)(ws + 29360128);     // 8MB    [ln1-gemm, gather]
    float* X2f    = (float*)(ws + 37748736);     // 8MB    [gather, w2-gemm]
    u16*   X2pad  = (u16*)(ws + 46137344);       // 4.72MB [gather, w1 gemm]
    u16*   Xbf    = (u16*)(ws + 50855936);       // 4MB    [convert, QKV gemm]
    float* ASRC   = (float*)(ws + 55050240);     // 256KB
    float* ADST   = (float*)(ws + 55312384);     // 256KB
    u16*   W_inp  = (u16*)(ws + 55574528);       // 393,216
    u16*   W_out  = (u16*)(ws + 55967744);       // 131,072
    u16*   W_lin  = (u16*)(ws + 56098816);       // 131,072
    u16*   W_w1   = (u16*)(ws + 56229888);       // 589,824 (1024 x 288)
    u16*   W_w2   = (u16*)(ws + 56819712);       // 524,288
    int*   COUNT  = (int*)(ws + 57344000);       // 32,768
    int*   OFFSET = (int*)(ws + 57376768);       // 36,864 (8193 used)
    int*   CURSOR = (int*)(ws + 57413632);       // 32,768
    int*   SORTED = (int*)(ws + 57446400);       // 1,081,344 -> ends 58,527,744

    // 1. conversions (x vectorized) + zero sort counters
    convert_all<<<5568, 256, 0, stream>>>(x, in_proj_w, out_proj_w, lin_w, w1, w2,
                                          Xbf, W_inp, W_out, W_lin, W_w1, W_w2, COUNT, CURSOR);
    // 2. QKV GEMM (768 blocks; V plane in interleaved layout) + edge histogram (1056 blocks)
    gemm_qkv_hist<<<1824, 256, 0, stream>>>(Xbf, W_inp, in_proj_b, QKV, edge_index, COUNT);
    // 3. flash attention (512 blocks, dbuf, async V staging) + offset scan (1 block)
    attn_mfma<<<513, 512, 0, stream>>>(QKV, CTX, COUNT, OFFSET);
    // 4. X1 = LN(x + CTX@Wo^T + b) -> X1f; chained XH = X1 @ Wl^T -> XH + scores (256 blocks)
    //    + edge scatter (528 blocks)
    gemm_ln0_xh<<<784, 512, 0, stream>>>(CTX, W_out, W_lin, out_proj_b, x, g1, be1,
                                         att_src, att_dst, X1f, XH, ASRC, ADST,
                                         edge_index, OFFSET, CURSOR, SORTED);
    // 5. gather + residual + LN2 -> X2f f32 + X2pad bf16 (K=288 w/ cond col)
    gat_gather_ln<<<4096, 256, 0, stream>>>(SORTED, OFFSET, ASRC, ADST, XH,
                                            X1f, gat_bias, g2, be2, condition, X2f, X2pad);
    // 6. H = relu(X2pad @ W_w1^T + bf1)
    gemm_w1<<<dim3(8, 64), 256, 0, stream>>>(X2pad, W_w1, bf1, Hb);
    // 7. out = LN(X2 + Hb@W_w2^T + bf2)
    gemm_ln2<<<256, 512, 0, stream>>>(Hb, 1024, W_w2, 1024, 1024, bf2, X2f, g3, be3, out);
}